// Round 1
// baseline (717.284 us; speedup 1.0000x reference)
//
#include <hip/hip_runtime.h>
#include <math.h>

#define DIMC 128

// ---------------- GEMM: out[M,128] = A[M,128] @ W[wrow0:wrow0+128, :128] (+bias) ----------------
__global__ __launch_bounds__(256) void gemm_k128(
    const float* __restrict__ A, const float* __restrict__ W, int wrow0,
    const float* __restrict__ bias, float* __restrict__ out, int M)
{
    __shared__ float Wl[DIMC * DIMC];  // 64 KiB
    const float4* Wv4 = (const float4*)(W + (long)wrow0 * DIMC);
    for (int i = threadIdx.x; i < DIMC * DIMC / 4; i += 256)
        ((float4*)Wl)[i] = Wv4[i];
    __syncthreads();

    int col = threadIdx.x & 127;
    int rg  = threadIdx.x >> 7;   // 0..1
    float b = bias ? bias[col] : 0.0f;
    int row0 = blockIdx.x * 32;

    for (int pass = 0; pass < 4; ++pass) {
        int r0 = row0 + pass * 8 + rg * 4;
        if (r0 + 3 >= M + 3) break;
        if (r0 >= M) continue;
        const float* a0 = A + (long)r0 * DIMC;
        float acc0 = b, acc1 = b, acc2 = b, acc3 = b;
        #pragma unroll 8
        for (int k = 0; k < DIMC; ++k) {
            float w = Wl[k * DIMC + col];
            acc0 = fmaf(a0[k],            w, acc0);
            acc1 = fmaf(a0[DIMC + k],     w, acc1);
            acc2 = fmaf(a0[2 * DIMC + k], w, acc2);
            acc3 = fmaf(a0[3 * DIMC + k], w, acc3);
        }
        // M is a multiple of 4 here (40000), bounds fine
        out[(long)(r0 + 0) * DIMC + col] = acc0;
        if (r0 + 1 < M) out[(long)(r0 + 1) * DIMC + col] = acc1;
        if (r0 + 2 < M) out[(long)(r0 + 2) * DIMC + col] = acc2;
        if (r0 + 3 < M) out[(long)(r0 + 3) * DIMC + col] = acc3;
    }
}

// ---------------- relation projections: Qre/Kre[t] = temb[t] @ W[128:,:] + b ----------------
__global__ __launch_bounds__(128) void rel_proj(
    const float* __restrict__ relemb, const float* __restrict__ selfrel,
    const float* __restrict__ Wq, const float* __restrict__ bq,
    const float* __restrict__ Wk, const float* __restrict__ bk,
    float* __restrict__ Qre, float* __restrict__ Kre, int R)
{
    int t = blockIdx.x;           // 0..R (R == self-relation)
    int c = threadIdx.x;
    const float* row = (t < R) ? (relemb + (long)t * DIMC) : selfrel;
    float aq = bq[c], ak = bk[c];
    for (int k = 0; k < DIMC; ++k) {
        float a = row[k];
        aq = fmaf(a, Wq[(long)(DIMC + k) * DIMC + c], aq);
        ak = fmaf(a, Wk[(long)(DIMC + k) * DIMC + c], ak);
    }
    Qre[(long)t * DIMC + c] = aq;
    Kre[(long)t * DIMC + c] = ak;
}

// ---------------- CSR build ----------------
__global__ void zero_int(int* __restrict__ p, int n) {
    int i = blockIdx.x * blockDim.x + threadIdx.x;
    if (i < n) p[i] = 0;
}

__global__ void hist_kernel(const int* __restrict__ dst, int* __restrict__ deg, int E) {
    int e = blockIdx.x * blockDim.x + threadIdx.x;
    if (e < E) atomicAdd(&deg[dst[e]], 1);
}

__global__ __launch_bounds__(1024) void scan_kernel(
    const int* __restrict__ deg, int* __restrict__ offs, int* __restrict__ cursor, int N)
{
    __shared__ int part[1024];
    int t = threadIdx.x;
    int chunk = (N + 1023) / 1024;
    int beg = t * chunk;
    int end = beg + chunk; if (end > N) end = N;
    int s = 0;
    for (int i = beg; i < end; ++i) s += deg[i];
    part[t] = s;
    __syncthreads();
    for (int d = 1; d < 1024; d <<= 1) {
        int v = (t >= d) ? part[t - d] : 0;
        __syncthreads();
        part[t] += v;
        __syncthreads();
    }
    int excl = (t == 0) ? 0 : part[t - 1];
    for (int i = beg; i < end; ++i) {
        offs[i] = excl;
        cursor[i] = excl;
        excl += deg[i];
    }
}

__global__ void scatter_kernel(const int* __restrict__ src, const int* __restrict__ dst,
                               const int* __restrict__ etype, int* __restrict__ cursor,
                               int* __restrict__ ssrc, int* __restrict__ stype, int E)
{
    int e = blockIdx.x * blockDim.x + threadIdx.x;
    if (e < E) {
        int d = dst[e];
        int p = atomicAdd(&cursor[d], 1);
        ssrc[p] = src[e];
        stype[p] = etype[e];
    }
}

// ---------------- per-node flash-style dual softmax + V aggregation ----------------
// one wave (64 lanes) per node; each lane owns 2 of the 128 feature dims
__global__ __launch_bounds__(256) void node_kernel(
    const float* __restrict__ Qn, const float* __restrict__ Kn,
    const float* __restrict__ Vn,
    const float* __restrict__ Qre, const float* __restrict__ Kre,
    const int* __restrict__ offs, const int* __restrict__ deg,
    const int* __restrict__ ssrc, const int* __restrict__ stype,
    float* __restrict__ out_sta, float* __restrict__ feat_dyn,
    int N, int R)
{
    int n = (blockIdx.x * blockDim.x + threadIdx.x) >> 6;
    int lane = threadIdx.x & 63;
    if (n >= N) return;

    const float scale = 0.08838834764831845f;  // 1/sqrt(128)
    int base = offs[n];
    int dcnt = deg[n];

    float2 qn = ((const float2*)(Qn + (long)n * DIMC))[lane];

    // self-loop edge: src = n, type = R
    float2 ks = ((const float2*)(Kn + (long)n * DIMC))[lane];
    float2 qr = ((const float2*)(Qre + (long)R * DIMC))[lane];
    float2 kr = ((const float2*)(Kre + (long)R * DIMC))[lane];
    float p = (qn.x + qr.x) * (ks.x + kr.x) + (qn.y + qr.y) * (ks.y + kr.y);
    #pragma unroll
    for (int m = 32; m >= 1; m >>= 1) p += __shfl_xor(p, m);
    float a_self = p * scale;

    float2 vs = ((const float2*)(Vn + (long)n * DIMC))[lane];
    float m_dyn = a_self, s_dyn = 1.0f;
    float m_sta = -a_self, s_sta = 1.0f;
    float2 accd = vs;   // exp(a_self - m_dyn) = 1
    float2 accs = vs;

    for (int i = 0; i < dcnt; ++i) {
        int s = ssrc[base + i];
        int t = stype[base + i];
        float2 kn = ((const float2*)(Kn + (long)s * DIMC))[lane];
        float2 q2 = ((const float2*)(Qre + (long)t * DIMC))[lane];
        float2 k2 = ((const float2*)(Kre + (long)t * DIMC))[lane];
        float pp = (qn.x + q2.x) * (kn.x + k2.x) + (qn.y + q2.y) * (kn.y + k2.y);
        #pragma unroll
        for (int m = 32; m >= 1; m >>= 1) pp += __shfl_xor(pp, m);
        float a = pp * scale;

        float2 v = ((const float2*)(Vn + (long)s * DIMC))[lane];

        // dyn stream (softmax over +a)
        float mn = fmaxf(m_dyn, a);
        float fd = __expf(m_dyn - mn);
        float wd = __expf(a - mn);
        s_dyn = s_dyn * fd + wd;
        accd.x = accd.x * fd + wd * v.x;
        accd.y = accd.y * fd + wd * v.y;
        m_dyn = mn;

        // sta stream (softmax over -a)
        float ms = fmaxf(m_sta, -a);
        float fs = __expf(m_sta - ms);
        float ws_ = __expf(-a - ms);
        s_sta = s_sta * fs + ws_;
        accs.x = accs.x * fs + ws_ * v.x;
        accs.y = accs.y * fs + ws_ * v.y;
        m_sta = ms;
    }

    float denom = (float)(dcnt + 1);   // counts include the self-loop; always >= 1
    float id_ = 1.0f / (s_dyn * denom);
    float is_ = 1.0f / (s_sta * denom);
    ((float2*)(out_sta + (long)n * DIMC))[lane] = make_float2(accs.x * is_, accs.y * is_);
    ((float2*)(feat_dyn + (long)n * DIMC))[lane] = make_float2(accd.x * id_, accd.y * id_);
}

// ---------------- launch ----------------
extern "C" void kernel_launch(void* const* d_in, const int* in_sizes, int n_in,
                              void* d_out, int out_size, void* d_ws, size_t ws_size,
                              hipStream_t stream)
{
    const float* curr    = (const float*)d_in[0];
    const float* last    = (const float*)d_in[1];
    const float* relemb  = (const float*)d_in[2];
    const float* selfrel = (const float*)d_in[3];
    const float* Wq      = (const float*)d_in[4];
    const float* bq      = (const float*)d_in[5];
    const float* Wk      = (const float*)d_in[6];
    const float* bk      = (const float*)d_in[7];
    const float* Wv      = (const float*)d_in[8];
    const float* bv      = (const float*)d_in[9];
    const float* dynw    = (const float*)d_in[10];
    const int*   eidx    = (const int*)d_in[11];
    const int*   etype   = (const int*)d_in[12];
    float* out = (float*)d_out;

    const int N = in_sizes[0] / DIMC;   // 40000
    const int E = in_sizes[12];         // 400000
    const int R = in_sizes[2] / DIMC;   // 502
    const int* esrc = eidx;
    const int* edst = eidx + E;

    float* ws = (float*)d_ws;
    size_t nd = (size_t)N * DIMC;
    float* Qn  = ws;
    float* Kn  = Qn + nd;
    float* Vn  = Kn + nd;
    float* Fd  = Vn + nd;
    float* Qre = Fd + nd;
    float* Kre = Qre + (size_t)(R + 1) * DIMC;
    int*   deg    = (int*)(Kre + (size_t)(R + 1) * DIMC);
    int*   offs   = deg + N;
    int*   cursor = offs + N;
    int*   ssrc   = cursor + N;
    int*   stype  = ssrc + E;

    int gblk = (N + 31) / 32;
    hipLaunchKernelGGL(gemm_k128, dim3(gblk), dim3(256), 0, stream,
                       curr, Wq, 0, (const float*)nullptr, Qn, N);
    hipLaunchKernelGGL(gemm_k128, dim3(gblk), dim3(256), 0, stream,
                       last, Wk, 0, (const float*)nullptr, Kn, N);
    hipLaunchKernelGGL(gemm_k128, dim3(gblk), dim3(256), 0, stream,
                       last, Wv, 0, bv, Vn, N);
    hipLaunchKernelGGL(rel_proj, dim3(R + 1), dim3(128), 0, stream,
                       relemb, selfrel, Wq, bq, Wk, bk, Qre, Kre, R);
    hipLaunchKernelGGL(zero_int, dim3((N + 255) / 256), dim3(256), 0, stream, deg, N);
    hipLaunchKernelGGL(hist_kernel, dim3((E + 255) / 256), dim3(256), 0, stream, edst, deg, E);
    hipLaunchKernelGGL(scan_kernel, dim3(1), dim3(1024), 0, stream, deg, offs, cursor, N);
    hipLaunchKernelGGL(scatter_kernel, dim3((E + 255) / 256), dim3(256), 0, stream,
                       esrc, edst, etype, cursor, ssrc, stype, E);
    hipLaunchKernelGGL(node_kernel, dim3((N + 3) / 4), dim3(256), 0, stream,
                       Qn, Kn, Vn, Qre, Kre, offs, deg, ssrc, stype, out, Fd, N, R);
    hipLaunchKernelGGL(gemm_k128, dim3(gblk), dim3(256), 0, stream,
                       Fd, dynw, 0, (const float*)nullptr, out + nd, N);
}

// Round 2
// 465.502 us; speedup vs baseline: 1.5409x; 1.5409x over previous
//
#include <hip/hip_runtime.h>
#include <math.h>

#define DIMC 128
#define BM 64
#define ASTRIDE (DIMC + 4)   // 132: rows 4 banks apart -> only free 2-way conflicts

// ---------------- register-tiled GEMM: out[M,128] = A[M,128] @ W[128,128] (+bias) ----------
// block = 256 threads, tile 64 rows x 128 cols; thread computes 4 rows x 8 cols.
// up to 3 independent (A,W,bias,out) configs selected by blockIdx.y.
struct Gemm3 {
    const float* A[3];
    const float* W[3];
    const float* bias[3];
    float*       out[3];
};

__global__ __launch_bounds__(256) void gemm_tiled_multi(Gemm3 args, int M)
{
    __shared__ float Ws[DIMC * DIMC];      // 64 KiB
    __shared__ float As[BM * ASTRIDE];     // 33 KiB

    const int which = blockIdx.y;
    const float* __restrict__ A    = args.A[which];
    const float* __restrict__ W    = args.W[which];
    const float* __restrict__ bias = args.bias[which];
    float* __restrict__ out        = args.out[which];

    // stage W (coalesced float4)
    const float4* Wv = (const float4*)W;
    #pragma unroll
    for (int i = threadIdx.x; i < DIMC * DIMC / 4; i += 256)
        ((float4*)Ws)[i] = Wv[i];

    // stage A tile: 64 rows x 128 cols -> padded stride 132
    const int row0 = blockIdx.x * BM;
    #pragma unroll
    for (int i = threadIdx.x; i < BM * DIMC / 4; i += 256) {
        int r  = i >> 5;          // 32 float4 per row
        int c4 = i & 31;
        float4 v = ((const float4*)(A + (long)(row0 + r) * DIMC))[c4];
        *((float4*)(As + r * ASTRIDE + c4 * 4)) = v;
    }
    __syncthreads();

    const int cg = threadIdx.x & 15;   // 8 cols: cg*8 .. cg*8+7
    const int rg = threadIdx.x >> 4;   // 4 rows: rg*4 .. rg*4+3

    float acc[4][8];
    #pragma unroll
    for (int j = 0; j < 8; ++j) {
        float b = bias ? bias[cg * 8 + j] : 0.0f;
        acc[0][j] = b; acc[1][j] = b; acc[2][j] = b; acc[3][j] = b;
    }

    const float* Ap = As + rg * 4 * ASTRIDE;
    const float* Wp = Ws + cg * 8;

    #pragma unroll 4
    for (int k = 0; k < DIMC; ++k) {
        float a0 = Ap[k];
        float a1 = Ap[ASTRIDE + k];
        float a2 = Ap[2 * ASTRIDE + k];
        float a3 = Ap[3 * ASTRIDE + k];
        float w[8];
        #pragma unroll
        for (int j = 0; j < 8; ++j) w[j] = Wp[k * DIMC + j];
        #pragma unroll
        for (int j = 0; j < 8; ++j) {
            acc[0][j] = fmaf(a0, w[j], acc[0][j]);
            acc[1][j] = fmaf(a1, w[j], acc[1][j]);
            acc[2][j] = fmaf(a2, w[j], acc[2][j]);
            acc[3][j] = fmaf(a3, w[j], acc[3][j]);
        }
    }

    #pragma unroll
    for (int i = 0; i < 4; ++i) {
        float* op = out + (long)(row0 + rg * 4 + i) * DIMC + cg * 8;
        ((float4*)op)[0] = make_float4(acc[i][0], acc[i][1], acc[i][2], acc[i][3]);
        ((float4*)op)[1] = make_float4(acc[i][4], acc[i][5], acc[i][6], acc[i][7]);
    }
}

// ---------------- relation projections: Qre/Kre[t] = temb[t] @ W[128:,:] + b ----------------
__global__ __launch_bounds__(128) void rel_proj(
    const float* __restrict__ relemb, const float* __restrict__ selfrel,
    const float* __restrict__ Wq, const float* __restrict__ bq,
    const float* __restrict__ Wk, const float* __restrict__ bk,
    float* __restrict__ Qre, float* __restrict__ Kre, int R)
{
    int t = blockIdx.x;           // 0..R (R == self-relation)
    int c = threadIdx.x;
    const float* row = (t < R) ? (relemb + (long)t * DIMC) : selfrel;
    float aq = bq[c], ak = bk[c];
    for (int k = 0; k < DIMC; ++k) {
        float a = row[k];
        aq = fmaf(a, Wq[(long)(DIMC + k) * DIMC + c], aq);
        ak = fmaf(a, Wk[(long)(DIMC + k) * DIMC + c], ak);
    }
    Qre[(long)t * DIMC + c] = aq;
    Kre[(long)t * DIMC + c] = ak;
}

// ---------------- CSR build ----------------
__global__ void zero_int(int* __restrict__ p, int n) {
    int i = blockIdx.x * blockDim.x + threadIdx.x;
    if (i < n) p[i] = 0;
}

__global__ void hist_kernel(const int* __restrict__ dst, int* __restrict__ deg, int E) {
    int e = blockIdx.x * blockDim.x + threadIdx.x;
    if (e < E) atomicAdd(&deg[dst[e]], 1);
}

__global__ __launch_bounds__(1024) void scan_kernel(
    const int* __restrict__ deg, int* __restrict__ offs, int* __restrict__ cursor, int N)
{
    __shared__ int part[1024];
    int t = threadIdx.x;
    int chunk = (N + 1023) / 1024;
    int beg = t * chunk;
    int end = beg + chunk; if (end > N) end = N;
    int s = 0;
    for (int i = beg; i < end; ++i) s += deg[i];
    part[t] = s;
    __syncthreads();
    for (int d = 1; d < 1024; d <<= 1) {
        int v = (t >= d) ? part[t - d] : 0;
        __syncthreads();
        part[t] += v;
        __syncthreads();
    }
    int excl = (t == 0) ? 0 : part[t - 1];
    for (int i = beg; i < end; ++i) {
        offs[i] = excl;
        cursor[i] = excl;
        excl += deg[i];
    }
}

__global__ void scatter_kernel(const int* __restrict__ src, const int* __restrict__ dst,
                               const int* __restrict__ etype, int* __restrict__ cursor,
                               int* __restrict__ ssrc, int* __restrict__ stype, int E)
{
    int e = blockIdx.x * blockDim.x + threadIdx.x;
    if (e < E) {
        int d = dst[e];
        int p = atomicAdd(&cursor[d], 1);
        ssrc[p] = src[e];
        stype[p] = etype[e];
    }
}

// ---------------- per-node flash-style dual softmax + V aggregation ----------------
// one wave (64 lanes) per node; each lane owns 2 of the 128 feature dims
__global__ __launch_bounds__(256) void node_kernel(
    const float* __restrict__ Qn, const float* __restrict__ Kn,
    const float* __restrict__ Vn,
    const float* __restrict__ Qre, const float* __restrict__ Kre,
    const int* __restrict__ offs, const int* __restrict__ deg,
    const int* __restrict__ ssrc, const int* __restrict__ stype,
    float* __restrict__ out_sta, float* __restrict__ feat_dyn,
    int N, int R)
{
    int n = (blockIdx.x * blockDim.x + threadIdx.x) >> 6;
    int lane = threadIdx.x & 63;
    if (n >= N) return;

    const float scale = 0.08838834764831845f;  // 1/sqrt(128)
    int base = offs[n];
    int dcnt = deg[n];

    float2 qn = ((const float2*)(Qn + (long)n * DIMC))[lane];

    // self-loop edge: src = n, type = R
    float2 ks = ((const float2*)(Kn + (long)n * DIMC))[lane];
    float2 qr = ((const float2*)(Qre + (long)R * DIMC))[lane];
    float2 kr = ((const float2*)(Kre + (long)R * DIMC))[lane];
    float p = (qn.x + qr.x) * (ks.x + kr.x) + (qn.y + qr.y) * (ks.y + kr.y);
    #pragma unroll
    for (int m = 32; m >= 1; m >>= 1) p += __shfl_xor(p, m);
    float a_self = p * scale;

    float2 vs = ((const float2*)(Vn + (long)n * DIMC))[lane];
    float m_dyn = a_self, s_dyn = 1.0f;
    float m_sta = -a_self, s_sta = 1.0f;
    float2 accd = vs;   // exp(a_self - m_dyn) = 1
    float2 accs = vs;

    for (int i = 0; i < dcnt; ++i) {
        int s = ssrc[base + i];
        int t = stype[base + i];
        float2 kn = ((const float2*)(Kn + (long)s * DIMC))[lane];
        float2 q2 = ((const float2*)(Qre + (long)t * DIMC))[lane];
        float2 k2 = ((const float2*)(Kre + (long)t * DIMC))[lane];
        float pp = (qn.x + q2.x) * (kn.x + k2.x) + (qn.y + q2.y) * (kn.y + k2.y);
        #pragma unroll
        for (int m = 32; m >= 1; m >>= 1) pp += __shfl_xor(pp, m);
        float a = pp * scale;

        float2 v = ((const float2*)(Vn + (long)s * DIMC))[lane];

        // dyn stream (softmax over +a)
        float mn = fmaxf(m_dyn, a);
        float fd = __expf(m_dyn - mn);
        float wd = __expf(a - mn);
        s_dyn = s_dyn * fd + wd;
        accd.x = accd.x * fd + wd * v.x;
        accd.y = accd.y * fd + wd * v.y;
        m_dyn = mn;

        // sta stream (softmax over -a)
        float ms = fmaxf(m_sta, -a);
        float fs = __expf(m_sta - ms);
        float ws_ = __expf(-a - ms);
        s_sta = s_sta * fs + ws_;
        accs.x = accs.x * fs + ws_ * v.x;
        accs.y = accs.y * fs + ws_ * v.y;
        m_sta = ms;
    }

    float denom = (float)(dcnt + 1);   // counts include the self-loop; always >= 1
    float id_ = 1.0f / (s_dyn * denom);
    float is_ = 1.0f / (s_sta * denom);
    ((float2*)(out_sta + (long)n * DIMC))[lane] = make_float2(accs.x * is_, accs.y * is_);
    ((float2*)(feat_dyn + (long)n * DIMC))[lane] = make_float2(accd.x * id_, accd.y * id_);
}

// ---------------- launch ----------------
extern "C" void kernel_launch(void* const* d_in, const int* in_sizes, int n_in,
                              void* d_out, int out_size, void* d_ws, size_t ws_size,
                              hipStream_t stream)
{
    const float* curr    = (const float*)d_in[0];
    const float* last    = (const float*)d_in[1];
    const float* relemb  = (const float*)d_in[2];
    const float* selfrel = (const float*)d_in[3];
    const float* Wq      = (const float*)d_in[4];
    const float* bq      = (const float*)d_in[5];
    const float* Wk      = (const float*)d_in[6];
    const float* bk      = (const float*)d_in[7];
    const float* Wv      = (const float*)d_in[8];
    const float* bv      = (const float*)d_in[9];
    const float* dynw    = (const float*)d_in[10];
    const int*   eidx    = (const int*)d_in[11];
    const int*   etype   = (const int*)d_in[12];
    float* out = (float*)d_out;

    const int N = in_sizes[0] / DIMC;   // 40000
    const int E = in_sizes[12];         // 400000
    const int R = in_sizes[2] / DIMC;   // 502
    const int* esrc = eidx;
    const int* edst = eidx + E;

    float* ws = (float*)d_ws;
    size_t nd = (size_t)N * DIMC;
    float* Qn  = ws;
    float* Kn  = Qn + nd;
    float* Vn  = Kn + nd;
    float* Fd  = Vn + nd;
    float* Qre = Fd + nd;
    float* Kre = Qre + (size_t)(R + 1) * DIMC;
    int*   deg    = (int*)(Kre + (size_t)(R + 1) * DIMC);
    int*   offs   = deg + N;
    int*   cursor = offs + N;
    int*   ssrc   = cursor + N;
    int*   stype  = ssrc + E;

    const int gblk = N / BM;   // 40000 / 64 = 625

    // fused Q/K/V projections (node parts)
    Gemm3 qkv;
    qkv.A[0] = curr;  qkv.W[0] = Wq;   qkv.bias[0] = nullptr; qkv.out[0] = Qn;
    qkv.A[1] = last;  qkv.W[1] = Wk;   qkv.bias[1] = nullptr; qkv.out[1] = Kn;
    qkv.A[2] = last;  qkv.W[2] = Wv;   qkv.bias[2] = bv;      qkv.out[2] = Vn;
    hipLaunchKernelGGL(gemm_tiled_multi, dim3(gblk, 3), dim3(256), 0, stream, qkv, N);

    hipLaunchKernelGGL(rel_proj, dim3(R + 1), dim3(128), 0, stream,
                       relemb, selfrel, Wq, bq, Wk, bk, Qre, Kre, R);
    hipLaunchKernelGGL(zero_int, dim3((N + 255) / 256), dim3(256), 0, stream, deg, N);
    hipLaunchKernelGGL(hist_kernel, dim3((E + 255) / 256), dim3(256), 0, stream, edst, deg, E);
    hipLaunchKernelGGL(scan_kernel, dim3(1), dim3(1024), 0, stream, deg, offs, cursor, N);
    hipLaunchKernelGGL(scatter_kernel, dim3((E + 255) / 256), dim3(256), 0, stream,
                       esrc, edst, etype, cursor, ssrc, stype, E);
    hipLaunchKernelGGL(node_kernel, dim3((N + 3) / 4), dim3(256), 0, stream,
                       Qn, Kn, Vn, Qre, Kre, offs, deg, ssrc, stype, out, Fd, N, R);

    // feat_dyn @ dyn_weight
    Gemm3 fin;
    fin.A[0] = Fd;  fin.W[0] = dynw; fin.bias[0] = nullptr; fin.out[0] = out + nd;
    fin.A[1] = Fd;  fin.W[1] = dynw; fin.bias[1] = nullptr; fin.out[1] = out + nd;
    fin.A[2] = Fd;  fin.W[2] = dynw; fin.bias[2] = nullptr; fin.out[2] = out + nd;
    hipLaunchKernelGGL(gemm_tiled_multi, dim3(gblk, 1), dim3(256), 0, stream, fin, N);
}

// Round 3
// 416.388 us; speedup vs baseline: 1.7226x; 1.1180x over previous
//
#include <hip/hip_runtime.h>
#include <math.h>

#define DIMC 128
#define BM 64
#define ASTRIDE (DIMC + 4)   // 132: float4-aligned (528B rows), rows 4 banks apart -> 2-way max (free)

// ---------------- register-tiled GEMM: out[M,128] = A[M,128] @ W[128,128] (+bias) ----------
// block = 256 threads, tile 64 rows x 128 cols; thread computes 4 rows x 8 cols
// (cols cg*4..cg*4+3 and 64+cg*4..64+cg*4+3 -> all LDS reads b128, <=2-way aliasing).
// W staged in two K-halves (32 KiB) so LDS total = 65 KiB -> 2 blocks/CU.
struct Gemm3 {
    const float* A[3];
    const float* W[3];
    const float* bias[3];
    float*       out[3];
};

__global__ __launch_bounds__(256, 2) void gemm_tiled_multi(Gemm3 args, int M)
{
    __shared__ float Ws[64 * DIMC];        // 32 KiB: one K-half of W
    __shared__ float As[BM * ASTRIDE];     // 33 KiB

    const int which = blockIdx.y;
    const float* __restrict__ A    = args.A[which];
    const float* __restrict__ W    = args.W[which];
    const float* __restrict__ bias = args.bias[which];
    float* __restrict__ out        = args.out[which];

    const int row0 = blockIdx.x * BM;

    // stage A tile: 64 rows x 128 cols -> padded stride 132
    #pragma unroll
    for (int i = threadIdx.x; i < BM * DIMC / 4; i += 256) {
        int r  = i >> 5;          // 32 float4 per row
        int c4 = i & 31;
        float4 v = ((const float4*)(A + (long)(row0 + r) * DIMC))[c4];
        *((float4*)(As + r * ASTRIDE + c4 * 4)) = v;
    }

    const int cg = threadIdx.x & 15;   // col groups: cg*4 and 64+cg*4
    const int rg = threadIdx.x >> 4;   // rows rg*4 .. rg*4+3

    float acc[4][8];
    #pragma unroll
    for (int j = 0; j < 4; ++j) {
        float b0 = bias ? bias[cg * 4 + j]      : 0.0f;
        float b1 = bias ? bias[64 + cg * 4 + j] : 0.0f;
        #pragma unroll
        for (int i = 0; i < 4; ++i) { acc[i][j] = b0; acc[i][4 + j] = b1; }
    }

    #pragma unroll
    for (int ph = 0; ph < 2; ++ph) {
        __syncthreads();   // As ready (ph0) / Ws safe to overwrite (ph1)
        const float4* Wv = (const float4*)(W + (long)ph * 64 * DIMC);
        #pragma unroll
        for (int i = threadIdx.x; i < 64 * DIMC / 4; i += 256)
            ((float4*)Ws)[i] = Wv[i];
        __syncthreads();

        const float* Ap = As + rg * 4 * ASTRIDE + ph * 64;

        #pragma unroll 2
        for (int k0 = 0; k0 < 64; k0 += 4) {
            float4 a0 = *(const float4*)(Ap + k0);
            float4 a1 = *(const float4*)(Ap + ASTRIDE + k0);
            float4 a2 = *(const float4*)(Ap + 2 * ASTRIDE + k0);
            float4 a3 = *(const float4*)(Ap + 3 * ASTRIDE + k0);
            #pragma unroll
            for (int kk = 0; kk < 4; ++kk) {
                float4 w0 = *(const float4*)(Ws + (k0 + kk) * DIMC + cg * 4);
                float4 w1 = *(const float4*)(Ws + (k0 + kk) * DIMC + 64 + cg * 4);
                float ar[4] = { ((const float*)&a0)[kk], ((const float*)&a1)[kk],
                                ((const float*)&a2)[kk], ((const float*)&a3)[kk] };
                #pragma unroll
                for (int i = 0; i < 4; ++i) {
                    acc[i][0] = fmaf(ar[i], w0.x, acc[i][0]);
                    acc[i][1] = fmaf(ar[i], w0.y, acc[i][1]);
                    acc[i][2] = fmaf(ar[i], w0.z, acc[i][2]);
                    acc[i][3] = fmaf(ar[i], w0.w, acc[i][3]);
                    acc[i][4] = fmaf(ar[i], w1.x, acc[i][4]);
                    acc[i][5] = fmaf(ar[i], w1.y, acc[i][5]);
                    acc[i][6] = fmaf(ar[i], w1.z, acc[i][6]);
                    acc[i][7] = fmaf(ar[i], w1.w, acc[i][7]);
                }
            }
        }
    }

    #pragma unroll
    for (int i = 0; i < 4; ++i) {
        float* op = out + (long)(row0 + rg * 4 + i) * DIMC;
        *((float4*)(op + cg * 4))      = make_float4(acc[i][0], acc[i][1], acc[i][2], acc[i][3]);
        *((float4*)(op + 64 + cg * 4)) = make_float4(acc[i][4], acc[i][5], acc[i][6], acc[i][7]);
    }
}

// ---------------- relation projections: Qre/Kre[t] = temb[t] @ W[128:,:] + b ----------------
__global__ __launch_bounds__(128) void rel_proj(
    const float* __restrict__ relemb, const float* __restrict__ selfrel,
    const float* __restrict__ Wq, const float* __restrict__ bq,
    const float* __restrict__ Wk, const float* __restrict__ bk,
    float* __restrict__ Qre, float* __restrict__ Kre, int R)
{
    int t = blockIdx.x;           // 0..R (R == self-relation)
    int c = threadIdx.x;
    const float* row = (t < R) ? (relemb + (long)t * DIMC) : selfrel;
    float aq = bq[c], ak = bk[c];
    for (int k = 0; k < DIMC; ++k) {
        float a = row[k];
        aq = fmaf(a, Wq[(long)(DIMC + k) * DIMC + c], aq);
        ak = fmaf(a, Wk[(long)(DIMC + k) * DIMC + c], ak);
    }
    Qre[(long)t * DIMC + c] = aq;
    Kre[(long)t * DIMC + c] = ak;
}

// ---------------- CSR build ----------------
__global__ void zero_int(int* __restrict__ p, int n) {
    int i = blockIdx.x * blockDim.x + threadIdx.x;
    if (i < n) p[i] = 0;
}

__global__ void hist_kernel(const int* __restrict__ dst, int* __restrict__ deg, int E) {
    int e = blockIdx.x * blockDim.x + threadIdx.x;
    if (e < E) atomicAdd(&deg[dst[e]], 1);
}

__global__ __launch_bounds__(1024) void scan_kernel(
    const int* __restrict__ deg, int* __restrict__ offs, int* __restrict__ cursor, int N)
{
    __shared__ int part[1024];
    int t = threadIdx.x;
    int chunk = (N + 1023) / 1024;
    int beg = t * chunk;
    int end = beg + chunk; if (end > N) end = N;
    int s = 0;
    for (int i = beg; i < end; ++i) s += deg[i];
    part[t] = s;
    __syncthreads();
    for (int d = 1; d < 1024; d <<= 1) {
        int v = (t >= d) ? part[t - d] : 0;
        __syncthreads();
        part[t] += v;
        __syncthreads();
    }
    int excl = (t == 0) ? 0 : part[t - 1];
    for (int i = beg; i < end; ++i) {
        offs[i] = excl;
        cursor[i] = excl;
        excl += deg[i];
    }
}

__global__ void scatter_kernel(const int* __restrict__ src, const int* __restrict__ dst,
                               const int* __restrict__ etype, int* __restrict__ cursor,
                               int* __restrict__ ssrc, int* __restrict__ stype, int E)
{
    int e = blockIdx.x * blockDim.x + threadIdx.x;
    if (e < E) {
        int d = dst[e];
        int p = atomicAdd(&cursor[d], 1);
        ssrc[p] = src[e];
        stype[p] = etype[e];
    }
}

// ---------------- per-node flash-style dual softmax + V aggregation ----------------
// one wave (64 lanes) per node; each lane owns 2 of the 128 feature dims
__global__ __launch_bounds__(256) void node_kernel(
    const float* __restrict__ Qn, const float* __restrict__ Kn,
    const float* __restrict__ Vn,
    const float* __restrict__ Qre, const float* __restrict__ Kre,
    const int* __restrict__ offs, const int* __restrict__ deg,
    const int* __restrict__ ssrc, const int* __restrict__ stype,
    float* __restrict__ out_sta, float* __restrict__ feat_dyn,
    int N, int R)
{
    int n = (blockIdx.x * blockDim.x + threadIdx.x) >> 6;
    int lane = threadIdx.x & 63;
    if (n >= N) return;

    const float scale = 0.08838834764831845f;  // 1/sqrt(128)
    int base = offs[n];
    int dcnt = deg[n];

    float2 qn = ((const float2*)(Qn + (long)n * DIMC))[lane];

    // self-loop edge: src = n, type = R
    float2 ks = ((const float2*)(Kn + (long)n * DIMC))[lane];
    float2 qr = ((const float2*)(Qre + (long)R * DIMC))[lane];
    float2 kr = ((const float2*)(Kre + (long)R * DIMC))[lane];
    float p = (qn.x + qr.x) * (ks.x + kr.x) + (qn.y + qr.y) * (ks.y + kr.y);
    #pragma unroll
    for (int m = 32; m >= 1; m >>= 1) p += __shfl_xor(p, m);
    float a_self = p * scale;

    float2 vs = ((const float2*)(Vn + (long)n * DIMC))[lane];
    float m_dyn = a_self, s_dyn = 1.0f;
    float m_sta = -a_self, s_sta = 1.0f;
    float2 accd = vs;   // exp(a_self - m_dyn) = 1
    float2 accs = vs;

    for (int i = 0; i < dcnt; ++i) {
        int s = ssrc[base + i];
        int t = stype[base + i];
        float2 kn = ((const float2*)(Kn + (long)s * DIMC))[lane];
        float2 q2 = ((const float2*)(Qre + (long)t * DIMC))[lane];
        float2 k2 = ((const float2*)(Kre + (long)t * DIMC))[lane];
        float pp = (qn.x + q2.x) * (kn.x + k2.x) + (qn.y + q2.y) * (kn.y + k2.y);
        #pragma unroll
        for (int m = 32; m >= 1; m >>= 1) pp += __shfl_xor(pp, m);
        float a = pp * scale;

        float2 v = ((const float2*)(Vn + (long)s * DIMC))[lane];

        // dyn stream (softmax over +a)
        float mn = fmaxf(m_dyn, a);
        float fd = __expf(m_dyn - mn);
        float wd = __expf(a - mn);
        s_dyn = s_dyn * fd + wd;
        accd.x = accd.x * fd + wd * v.x;
        accd.y = accd.y * fd + wd * v.y;
        m_dyn = mn;

        // sta stream (softmax over -a)
        float ms = fmaxf(m_sta, -a);
        float fs = __expf(m_sta - ms);
        float ws_ = __expf(-a - ms);
        s_sta = s_sta * fs + ws_;
        accs.x = accs.x * fs + ws_ * v.x;
        accs.y = accs.y * fs + ws_ * v.y;
        m_sta = ms;
    }

    float denom = (float)(dcnt + 1);   // counts include the self-loop; always >= 1
    float id_ = 1.0f / (s_dyn * denom);
    float is_ = 1.0f / (s_sta * denom);
    ((float2*)(out_sta + (long)n * DIMC))[lane] = make_float2(accs.x * is_, accs.y * is_);
    ((float2*)(feat_dyn + (long)n * DIMC))[lane] = make_float2(accd.x * id_, accd.y * id_);
}

// ---------------- launch ----------------
extern "C" void kernel_launch(void* const* d_in, const int* in_sizes, int n_in,
                              void* d_out, int out_size, void* d_ws, size_t ws_size,
                              hipStream_t stream)
{
    const float* curr    = (const float*)d_in[0];
    const float* last    = (const float*)d_in[1];
    const float* relemb  = (const float*)d_in[2];
    const float* selfrel = (const float*)d_in[3];
    const float* Wq      = (const float*)d_in[4];
    const float* bq      = (const float*)d_in[5];
    const float* Wk      = (const float*)d_in[6];
    const float* bk      = (const float*)d_in[7];
    const float* Wv      = (const float*)d_in[8];
    const float* bv      = (const float*)d_in[9];
    const float* dynw    = (const float*)d_in[10];
    const int*   eidx    = (const int*)d_in[11];
    const int*   etype   = (const int*)d_in[12];
    float* out = (float*)d_out;

    const int N = in_sizes[0] / DIMC;   // 40000
    const int E = in_sizes[12];         // 400000
    const int R = in_sizes[2] / DIMC;   // 502
    const int* esrc = eidx;
    const int* edst = eidx + E;

    float* ws = (float*)d_ws;
    size_t nd = (size_t)N * DIMC;
    float* Qn  = ws;
    float* Kn  = Qn + nd;
    float* Vn  = Kn + nd;
    float* Fd  = Vn + nd;
    float* Qre = Fd + nd;
    float* Kre = Qre + (size_t)(R + 1) * DIMC;
    int*   deg    = (int*)(Kre + (size_t)(R + 1) * DIMC);
    int*   offs   = deg + N;
    int*   cursor = offs + N;
    int*   ssrc   = cursor + N;
    int*   stype  = ssrc + E;

    const int gblk = N / BM;   // 40000 / 64 = 625

    // fused Q/K/V projections (node parts)
    Gemm3 qkv;
    qkv.A[0] = curr;  qkv.W[0] = Wq;   qkv.bias[0] = nullptr; qkv.out[0] = Qn;
    qkv.A[1] = last;  qkv.W[1] = Wk;   qkv.bias[1] = nullptr; qkv.out[1] = Kn;
    qkv.A[2] = last;  qkv.W[2] = Wv;   qkv.bias[2] = bv;      qkv.out[2] = Vn;
    hipLaunchKernelGGL(gemm_tiled_multi, dim3(gblk, 3), dim3(256), 0, stream, qkv, N);

    hipLaunchKernelGGL(rel_proj, dim3(R + 1), dim3(128), 0, stream,
                       relemb, selfrel, Wq, bq, Wk, bk, Qre, Kre, R);
    hipLaunchKernelGGL(zero_int, dim3((N + 255) / 256), dim3(256), 0, stream, deg, N);
    hipLaunchKernelGGL(hist_kernel, dim3((E + 255) / 256), dim3(256), 0, stream, edst, deg, E);
    hipLaunchKernelGGL(scan_kernel, dim3(1), dim3(1024), 0, stream, deg, offs, cursor, N);
    hipLaunchKernelGGL(scatter_kernel, dim3((E + 255) / 256), dim3(256), 0, stream,
                       esrc, edst, etype, cursor, ssrc, stype, E);
    hipLaunchKernelGGL(node_kernel, dim3((N + 3) / 4), dim3(256), 0, stream,
                       Qn, Kn, Vn, Qre, Kre, offs, deg, ssrc, stype, out, Fd, N, R);

    // feat_dyn @ dyn_weight
    Gemm3 fin;
    fin.A[0] = Fd;  fin.W[0] = dynw; fin.bias[0] = nullptr; fin.out[0] = out + nd;
    fin.A[1] = Fd;  fin.W[1] = dynw; fin.bias[1] = nullptr; fin.out[1] = out + nd;
    fin.A[2] = Fd;  fin.W[2] = dynw; fin.bias[2] = nullptr; fin.out[2] = out + nd;
    hipLaunchKernelGGL(gemm_tiled_multi, dim3(gblk, 1), dim3(256), 0, stream, fin, N);
}

// Round 4
// 329.043 us; speedup vs baseline: 2.1799x; 1.2655x over previous
//
#include <hip/hip_runtime.h>
#include <math.h>

#define DIMC 128
#define BM 64
#define ASTRIDE (DIMC + 4)   // 132: float4-aligned rows, 2-way LDS aliasing max (free)

// ---------------- register-tiled GEMM: out[M,128] = A[M,128] @ W[128,128] (+bias) ----------
struct Gemm3 {
    const float* A[3];
    const float* W[3];
    const float* bias[3];
    float*       out[3];
};

__global__ __launch_bounds__(256, 2) void gemm_tiled_multi(Gemm3 args, int M)
{
    __shared__ float Ws[64 * DIMC];        // 32 KiB: one K-half of W
    __shared__ float As[BM * ASTRIDE];     // 33 KiB

    const int which = blockIdx.y;
    const float* __restrict__ A    = args.A[which];
    const float* __restrict__ W    = args.W[which];
    const float* __restrict__ bias = args.bias[which];
    float* __restrict__ out        = args.out[which];

    const int row0 = blockIdx.x * BM;

    #pragma unroll
    for (int i = threadIdx.x; i < BM * DIMC / 4; i += 256) {
        int r  = i >> 5;
        int c4 = i & 31;
        float4 v = ((const float4*)(A + (long)(row0 + r) * DIMC))[c4];
        *((float4*)(As + r * ASTRIDE + c4 * 4)) = v;
    }

    const int cg = threadIdx.x & 15;
    const int rg = threadIdx.x >> 4;

    float acc[4][8];
    #pragma unroll
    for (int j = 0; j < 4; ++j) {
        float b0 = bias ? bias[cg * 4 + j]      : 0.0f;
        float b1 = bias ? bias[64 + cg * 4 + j] : 0.0f;
        #pragma unroll
        for (int i = 0; i < 4; ++i) { acc[i][j] = b0; acc[i][4 + j] = b1; }
    }

    #pragma unroll
    for (int ph = 0; ph < 2; ++ph) {
        __syncthreads();
        const float4* Wv = (const float4*)(W + (long)ph * 64 * DIMC);
        #pragma unroll
        for (int i = threadIdx.x; i < 64 * DIMC / 4; i += 256)
            ((float4*)Ws)[i] = Wv[i];
        __syncthreads();

        const float* Ap = As + rg * 4 * ASTRIDE + ph * 64;

        #pragma unroll 2
        for (int k0 = 0; k0 < 64; k0 += 4) {
            float4 a0 = *(const float4*)(Ap + k0);
            float4 a1 = *(const float4*)(Ap + ASTRIDE + k0);
            float4 a2 = *(const float4*)(Ap + 2 * ASTRIDE + k0);
            float4 a3 = *(const float4*)(Ap + 3 * ASTRIDE + k0);
            #pragma unroll
            for (int kk = 0; kk < 4; ++kk) {
                float4 w0 = *(const float4*)(Ws + (k0 + kk) * DIMC + cg * 4);
                float4 w1 = *(const float4*)(Ws + (k0 + kk) * DIMC + 64 + cg * 4);
                float ar[4] = { ((const float*)&a0)[kk], ((const float*)&a1)[kk],
                                ((const float*)&a2)[kk], ((const float*)&a3)[kk] };
                #pragma unroll
                for (int i = 0; i < 4; ++i) {
                    acc[i][0] = fmaf(ar[i], w0.x, acc[i][0]);
                    acc[i][1] = fmaf(ar[i], w0.y, acc[i][1]);
                    acc[i][2] = fmaf(ar[i], w0.z, acc[i][2]);
                    acc[i][3] = fmaf(ar[i], w0.w, acc[i][3]);
                    acc[i][4] = fmaf(ar[i], w1.x, acc[i][4]);
                    acc[i][5] = fmaf(ar[i], w1.y, acc[i][5]);
                    acc[i][6] = fmaf(ar[i], w1.z, acc[i][6]);
                    acc[i][7] = fmaf(ar[i], w1.w, acc[i][7]);
                }
            }
        }
    }

    #pragma unroll
    for (int i = 0; i < 4; ++i) {
        float* op = out + (long)(row0 + rg * 4 + i) * DIMC;
        *((float4*)(op + cg * 4))      = make_float4(acc[i][0], acc[i][1], acc[i][2], acc[i][3]);
        *((float4*)(op + 64 + cg * 4)) = make_float4(acc[i][4], acc[i][5], acc[i][6], acc[i][7]);
    }
}

// ---------------- relation projections ----------------
__global__ __launch_bounds__(128) void rel_proj(
    const float* __restrict__ relemb, const float* __restrict__ selfrel,
    const float* __restrict__ Wq, const float* __restrict__ bq,
    const float* __restrict__ Wk, const float* __restrict__ bk,
    float* __restrict__ Qre, float* __restrict__ Kre, int R)
{
    int t = blockIdx.x;
    int c = threadIdx.x;
    const float* row = (t < R) ? (relemb + (long)t * DIMC) : selfrel;
    float aq = bq[c], ak = bk[c];
    for (int k = 0; k < DIMC; ++k) {
        float a = row[k];
        aq = fmaf(a, Wq[(long)(DIMC + k) * DIMC + c], aq);
        ak = fmaf(a, Wk[(long)(DIMC + k) * DIMC + c], ak);
    }
    Qre[(long)t * DIMC + c] = aq;
    Kre[(long)t * DIMC + c] = ak;
}

// ---------------- CSR build ----------------
__global__ void zero_int(int* __restrict__ p, int n) {
    int i = blockIdx.x * blockDim.x + threadIdx.x;
    if (i < n) p[i] = 0;
}

__global__ void hist_kernel(const int* __restrict__ dst, int* __restrict__ deg, int E) {
    int e = blockIdx.x * blockDim.x + threadIdx.x;
    if (e < E) atomicAdd(&deg[dst[e]], 1);
}

// two-level scan: 1024 elements / block of 256 threads (4 per thread)
__global__ __launch_bounds__(256) void partial_sums(const int* __restrict__ deg,
                                                    int* __restrict__ partial, int N)
{
    __shared__ int sh[256];
    int t = threadIdx.x;
    int beg = blockIdx.x * 1024 + t * 4;
    int s = 0;
    if (beg + 3 < N) { int4 v = *(const int4*)(deg + beg); s = v.x + v.y + v.z + v.w; }
    else { for (int j = 0; j < 4; ++j) if (beg + j < N) s += deg[beg + j]; }
    sh[t] = s;
    __syncthreads();
    for (int d = 128; d >= 1; d >>= 1) {
        if (t < d) sh[t] += sh[t + d];
        __syncthreads();
    }
    if (t == 0) partial[blockIdx.x] = sh[0];
}

__global__ __launch_bounds__(256) void scan_partials(int* __restrict__ partial, int nb)
{
    __shared__ int sh[256];
    int t = threadIdx.x;
    sh[t] = (t < nb) ? partial[t] : 0;
    __syncthreads();
    for (int d = 1; d < 256; d <<= 1) {
        int v = (t >= d) ? sh[t - d] : 0;
        __syncthreads();
        sh[t] += v;
        __syncthreads();
    }
    if (t < nb) partial[t] = (t == 0) ? 0 : sh[t - 1];   // exclusive base per block
}

__global__ __launch_bounds__(256) void write_offsets(const int* __restrict__ deg,
                                                     const int* __restrict__ partial,
                                                     int* __restrict__ offs,
                                                     int* __restrict__ cursor, int N)
{
    __shared__ int sh[256];
    int t = threadIdx.x;
    int beg = blockIdx.x * 1024 + t * 4;
    int d0 = 0, d1 = 0, d2 = 0, d3 = 0;
    if (beg + 3 < N) { int4 v = *(const int4*)(deg + beg); d0 = v.x; d1 = v.y; d2 = v.z; d3 = v.w; }
    else {
        if (beg < N)     d0 = deg[beg];
        if (beg + 1 < N) d1 = deg[beg + 1];
        if (beg + 2 < N) d2 = deg[beg + 2];
        if (beg + 3 < N) d3 = deg[beg + 3];
    }
    int s = d0 + d1 + d2 + d3;
    sh[t] = s;
    __syncthreads();
    for (int d = 1; d < 256; d <<= 1) {
        int v = (t >= d) ? sh[t - d] : 0;
        __syncthreads();
        sh[t] += v;
        __syncthreads();
    }
    int base = partial[blockIdx.x] + sh[t] - s;
    int o0 = base, o1 = o0 + d0, o2 = o1 + d1, o3 = o2 + d2;
    if (beg < N)     { offs[beg]     = o0; cursor[beg]     = o0; }
    if (beg + 1 < N) { offs[beg + 1] = o1; cursor[beg + 1] = o1; }
    if (beg + 2 < N) { offs[beg + 2] = o2; cursor[beg + 2] = o2; }
    if (beg + 3 < N) { offs[beg + 3] = o3; cursor[beg + 3] = o3; }
}

__global__ void scatter_kernel(const int* __restrict__ src, const int* __restrict__ dst,
                               const int* __restrict__ etype, int* __restrict__ cursor,
                               int* __restrict__ ssrc, int* __restrict__ stype, int E)
{
    int e = blockIdx.x * blockDim.x + threadIdx.x;
    if (e < E) {
        int d = dst[e];
        int p = atomicAdd(&cursor[d], 1);
        ssrc[p] = src[e];
        stype[p] = etype[e];
    }
}

// ---------------- per-node flash-style dual softmax + V aggregation ----------------
// one wave per node, lane owns 2 dims; edges processed in chunks of 4 for MLP + ILP
__global__ __launch_bounds__(256) void node_kernel(
    const float* __restrict__ Qn, const float* __restrict__ Kn,
    const float* __restrict__ Vn,
    const float* __restrict__ Qre, const float* __restrict__ Kre,
    const int* __restrict__ offs, const int* __restrict__ deg,
    const int* __restrict__ ssrc, const int* __restrict__ stype,
    float* __restrict__ out_sta, float* __restrict__ feat_dyn,
    int N, int R)
{
    int n = (blockIdx.x * blockDim.x + threadIdx.x) >> 6;
    int lane = threadIdx.x & 63;
    if (n >= N) return;

    const float scale = 0.08838834764831845f;  // 1/sqrt(128)
    int base = offs[n];
    int dcnt = deg[n];

    float2 qn = ((const float2*)(Qn + (long)n * DIMC))[lane];

    // self-loop edge: src = n, type = R
    float2 ks = ((const float2*)(Kn + (long)n * DIMC))[lane];
    float2 qr = ((const float2*)(Qre + (long)R * DIMC))[lane];
    float2 kr = ((const float2*)(Kre + (long)R * DIMC))[lane];
    float p = (qn.x + qr.x) * (ks.x + kr.x) + (qn.y + qr.y) * (ks.y + kr.y);
    #pragma unroll
    for (int m = 32; m >= 1; m >>= 1) p += __shfl_xor(p, m);
    float a_self = p * scale;

    float2 vs = ((const float2*)(Vn + (long)n * DIMC))[lane];
    float m_dyn = a_self, s_dyn = 1.0f;
    float m_sta = -a_self, s_sta = 1.0f;
    float2 accd = vs;
    float2 accs = vs;

    int i = 0;
    for (; i + 4 <= dcnt; i += 4) {
        int s0 = ssrc[base + i],     s1 = ssrc[base + i + 1];
        int s2 = ssrc[base + i + 2], s3 = ssrc[base + i + 3];
        int t0 = stype[base + i],     t1 = stype[base + i + 1];
        int t2 = stype[base + i + 2], t3 = stype[base + i + 3];

        float2 kn0 = ((const float2*)(Kn + (long)s0 * DIMC))[lane];
        float2 kn1 = ((const float2*)(Kn + (long)s1 * DIMC))[lane];
        float2 kn2 = ((const float2*)(Kn + (long)s2 * DIMC))[lane];
        float2 kn3 = ((const float2*)(Kn + (long)s3 * DIMC))[lane];
        float2 q0 = ((const float2*)(Qre + (long)t0 * DIMC))[lane];
        float2 q1 = ((const float2*)(Qre + (long)t1 * DIMC))[lane];
        float2 q2 = ((const float2*)(Qre + (long)t2 * DIMC))[lane];
        float2 q3 = ((const float2*)(Qre + (long)t3 * DIMC))[lane];
        float2 k0 = ((const float2*)(Kre + (long)t0 * DIMC))[lane];
        float2 k1 = ((const float2*)(Kre + (long)t1 * DIMC))[lane];
        float2 k2 = ((const float2*)(Kre + (long)t2 * DIMC))[lane];
        float2 k3 = ((const float2*)(Kre + (long)t3 * DIMC))[lane];
        float2 v0 = ((const float2*)(Vn + (long)s0 * DIMC))[lane];
        float2 v1 = ((const float2*)(Vn + (long)s1 * DIMC))[lane];
        float2 v2 = ((const float2*)(Vn + (long)s2 * DIMC))[lane];
        float2 v3 = ((const float2*)(Vn + (long)s3 * DIMC))[lane];

        float p0 = (qn.x + q0.x) * (kn0.x + k0.x) + (qn.y + q0.y) * (kn0.y + k0.y);
        float p1 = (qn.x + q1.x) * (kn1.x + k1.x) + (qn.y + q1.y) * (kn1.y + k1.y);
        float p2 = (qn.x + q2.x) * (kn2.x + k2.x) + (qn.y + q2.y) * (kn2.y + k2.y);
        float p3 = (qn.x + q3.x) * (kn3.x + k3.x) + (qn.y + q3.y) * (kn3.y + k3.y);
        #pragma unroll
        for (int m = 32; m >= 1; m >>= 1) {
            p0 += __shfl_xor(p0, m);
            p1 += __shfl_xor(p1, m);
            p2 += __shfl_xor(p2, m);
            p3 += __shfl_xor(p3, m);
        }
        float a0 = p0 * scale, a1 = p1 * scale, a2 = p2 * scale, a3 = p3 * scale;

        // dyn stream (softmax over +a)
        float mx = fmaxf(fmaxf(a0, a1), fmaxf(a2, a3));
        float mn = fmaxf(m_dyn, mx);
        float f  = __expf(m_dyn - mn);
        float w0 = __expf(a0 - mn), w1 = __expf(a1 - mn);
        float w2 = __expf(a2 - mn), w3 = __expf(a3 - mn);
        s_dyn = fmaf(s_dyn, f, (w0 + w1) + (w2 + w3));
        accd.x = fmaf(accd.x, f, fmaf(w0, v0.x, fmaf(w1, v1.x, fmaf(w2, v2.x, w3 * v3.x))));
        accd.y = fmaf(accd.y, f, fmaf(w0, v0.y, fmaf(w1, v1.y, fmaf(w2, v2.y, w3 * v3.y))));
        m_dyn = mn;

        // sta stream (softmax over -a)
        float nmx = -fminf(fminf(a0, a1), fminf(a2, a3));
        float ms = fmaxf(m_sta, nmx);
        float fs = __expf(m_sta - ms);
        float u0 = __expf(-a0 - ms), u1 = __expf(-a1 - ms);
        float u2 = __expf(-a2 - ms), u3 = __expf(-a3 - ms);
        s_sta = fmaf(s_sta, fs, (u0 + u1) + (u2 + u3));
        accs.x = fmaf(accs.x, fs, fmaf(u0, v0.x, fmaf(u1, v1.x, fmaf(u2, v2.x, u3 * v3.x))));
        accs.y = fmaf(accs.y, fs, fmaf(u0, v0.y, fmaf(u1, v1.y, fmaf(u2, v2.y, u3 * v3.y))));
        m_sta = ms;
    }

    for (; i < dcnt; ++i) {
        int s = ssrc[base + i];
        int t = stype[base + i];
        float2 kn = ((const float2*)(Kn + (long)s * DIMC))[lane];
        float2 q2 = ((const float2*)(Qre + (long)t * DIMC))[lane];
        float2 k2 = ((const float2*)(Kre + (long)t * DIMC))[lane];
        float pp = (qn.x + q2.x) * (kn.x + k2.x) + (qn.y + q2.y) * (kn.y + k2.y);
        #pragma unroll
        for (int m = 32; m >= 1; m >>= 1) pp += __shfl_xor(pp, m);
        float a = pp * scale;

        float2 v = ((const float2*)(Vn + (long)s * DIMC))[lane];

        float mn = fmaxf(m_dyn, a);
        float fd = __expf(m_dyn - mn);
        float wd = __expf(a - mn);
        s_dyn = fmaf(s_dyn, fd, wd);
        accd.x = fmaf(accd.x, fd, wd * v.x);
        accd.y = fmaf(accd.y, fd, wd * v.y);
        m_dyn = mn;

        float ms = fmaxf(m_sta, -a);
        float fs = __expf(m_sta - ms);
        float ws_ = __expf(-a - ms);
        s_sta = fmaf(s_sta, fs, ws_);
        accs.x = fmaf(accs.x, fs, ws_ * v.x);
        accs.y = fmaf(accs.y, fs, ws_ * v.y);
        m_sta = ms;
    }

    float denom = (float)(dcnt + 1);
    float id_ = 1.0f / (s_dyn * denom);
    float is_ = 1.0f / (s_sta * denom);
    ((float2*)(out_sta + (long)n * DIMC))[lane] = make_float2(accs.x * is_, accs.y * is_);
    ((float2*)(feat_dyn + (long)n * DIMC))[lane] = make_float2(accd.x * id_, accd.y * id_);
}

// ---------------- launch ----------------
extern "C" void kernel_launch(void* const* d_in, const int* in_sizes, int n_in,
                              void* d_out, int out_size, void* d_ws, size_t ws_size,
                              hipStream_t stream)
{
    const float* curr    = (const float*)d_in[0];
    const float* last    = (const float*)d_in[1];
    const float* relemb  = (const float*)d_in[2];
    const float* selfrel = (const float*)d_in[3];
    const float* Wq      = (const float*)d_in[4];
    const float* bq      = (const float*)d_in[5];
    const float* Wk      = (const float*)d_in[6];
    const float* bk      = (const float*)d_in[7];
    const float* Wv      = (const float*)d_in[8];
    const float* bv      = (const float*)d_in[9];
    const float* dynw    = (const float*)d_in[10];
    const int*   eidx    = (const int*)d_in[11];
    const int*   etype   = (const int*)d_in[12];
    float* out = (float*)d_out;

    const int N = in_sizes[0] / DIMC;   // 40000
    const int E = in_sizes[12];         // 400000
    const int R = in_sizes[2] / DIMC;   // 502
    const int* esrc = eidx;
    const int* edst = eidx + E;

    float* ws = (float*)d_ws;
    size_t nd = (size_t)N * DIMC;
    float* Qn  = ws;
    float* Kn  = Qn + nd;
    float* Vn  = Kn + nd;
    float* Fd  = Vn + nd;
    float* Qre = Fd + nd;
    float* Kre = Qre + (size_t)(R + 1) * DIMC;
    int*   deg    = (int*)(Kre + (size_t)(R + 1) * DIMC);
    int*   offs   = deg + N;
    int*   cursor = offs + N;
    int*   ssrc   = cursor + N;
    int*   stype  = ssrc + E;
    int*   partial = stype + E;

    const int gblk = N / BM;                 // 625
    const int sblk = (N + 1023) / 1024;      // 40

    Gemm3 qkv;
    qkv.A[0] = curr;  qkv.W[0] = Wq;   qkv.bias[0] = nullptr; qkv.out[0] = Qn;
    qkv.A[1] = last;  qkv.W[1] = Wk;   qkv.bias[1] = nullptr; qkv.out[1] = Kn;
    qkv.A[2] = last;  qkv.W[2] = Wv;   qkv.bias[2] = bv;      qkv.out[2] = Vn;
    hipLaunchKernelGGL(gemm_tiled_multi, dim3(gblk, 3), dim3(256), 0, stream, qkv, N);

    hipLaunchKernelGGL(rel_proj, dim3(R + 1), dim3(128), 0, stream,
                       relemb, selfrel, Wq, bq, Wk, bk, Qre, Kre, R);
    hipLaunchKernelGGL(zero_int, dim3((N + 255) / 256), dim3(256), 0, stream, deg, N);
    hipLaunchKernelGGL(hist_kernel, dim3((E + 255) / 256), dim3(256), 0, stream, edst, deg, E);
    hipLaunchKernelGGL(partial_sums, dim3(sblk), dim3(256), 0, stream, deg, partial, N);
    hipLaunchKernelGGL(scan_partials, dim3(1), dim3(256), 0, stream, partial, sblk);
    hipLaunchKernelGGL(write_offsets, dim3(sblk), dim3(256), 0, stream,
                       deg, partial, offs, cursor, N);
    hipLaunchKernelGGL(scatter_kernel, dim3((E + 255) / 256), dim3(256), 0, stream,
                       esrc, edst, etype, cursor, ssrc, stype, E);
    hipLaunchKernelGGL(node_kernel, dim3((N + 3) / 4), dim3(256), 0, stream,
                       Qn, Kn, Vn, Qre, Kre, offs, deg, ssrc, stype, out, Fd, N, R);

    Gemm3 fin;
    fin.A[0] = Fd;  fin.W[0] = dynw; fin.bias[0] = nullptr; fin.out[0] = out + nd;
    fin.A[1] = Fd;  fin.W[1] = dynw; fin.bias[1] = nullptr; fin.out[1] = out + nd;
    fin.A[2] = Fd;  fin.W[2] = dynw; fin.bias[2] = nullptr; fin.out[2] = out + nd;
    hipLaunchKernelGGL(gemm_tiled_multi, dim3(gblk, 1), dim3(256), 0, stream, fin, N);
}

// Round 5
// 295.083 us; speedup vs baseline: 2.4308x; 1.1151x over previous
//
#include <hip/hip_runtime.h>
#include <math.h>

#define DIMC 128
#define BM 64
#define ASTRIDE (DIMC + 4)   // 132: float4-aligned rows, 2-way LDS aliasing max (free)

// bf16 helpers (round-to-nearest-even pack, bit-shift unpack)
static __device__ __forceinline__ unsigned short f2bf(float x) {
    union { float f; unsigned int u; } v; v.f = x;
    unsigned int r = v.u + 0x7FFFu + ((v.u >> 16) & 1u);
    return (unsigned short)(r >> 16);
}
static __device__ __forceinline__ float2 bf2f2(unsigned int u) {
    union { unsigned int i; float f; } a, b;
    a.i = u << 16; b.i = u & 0xFFFF0000u;
    return make_float2(a.f, b.f);
}

// ---------------- register-tiled GEMM: out[M,128] = A[M,128] @ W[128,128] (+bias) ----------
// obf[which] != 0 -> write bf16 (packed ushort rows), else f32.
struct Gemm3 {
    const float* A[3];
    const float* W[3];
    const float* bias[3];
    float*       out[3];
    int          obf[3];
};

__global__ __launch_bounds__(256, 2) void gemm_tiled_multi(Gemm3 args, int M)
{
    __shared__ float Ws[64 * DIMC];        // 32 KiB: one K-half of W
    __shared__ float As[BM * ASTRIDE];     // 33 KiB

    const int which = blockIdx.y;
    const float* __restrict__ A    = args.A[which];
    const float* __restrict__ W    = args.W[which];
    const float* __restrict__ bias = args.bias[which];
    float* __restrict__ out        = args.out[which];
    const int obf                  = args.obf[which];

    const int row0 = blockIdx.x * BM;

    #pragma unroll
    for (int i = threadIdx.x; i < BM * DIMC / 4; i += 256) {
        int r  = i >> 5;
        int c4 = i & 31;
        float4 v = ((const float4*)(A + (long)(row0 + r) * DIMC))[c4];
        *((float4*)(As + r * ASTRIDE + c4 * 4)) = v;
    }

    const int cg = threadIdx.x & 15;
    const int rg = threadIdx.x >> 4;

    float acc[4][8];
    #pragma unroll
    for (int j = 0; j < 4; ++j) {
        float b0 = bias ? bias[cg * 4 + j]      : 0.0f;
        float b1 = bias ? bias[64 + cg * 4 + j] : 0.0f;
        #pragma unroll
        for (int i = 0; i < 4; ++i) { acc[i][j] = b0; acc[i][4 + j] = b1; }
    }

    #pragma unroll
    for (int ph = 0; ph < 2; ++ph) {
        __syncthreads();
        const float4* Wv = (const float4*)(W + (long)ph * 64 * DIMC);
        #pragma unroll
        for (int i = threadIdx.x; i < 64 * DIMC / 4; i += 256)
            ((float4*)Ws)[i] = Wv[i];
        __syncthreads();

        const float* Ap = As + rg * 4 * ASTRIDE + ph * 64;

        #pragma unroll 2
        for (int k0 = 0; k0 < 64; k0 += 4) {
            float4 a0 = *(const float4*)(Ap + k0);
            float4 a1 = *(const float4*)(Ap + ASTRIDE + k0);
            float4 a2 = *(const float4*)(Ap + 2 * ASTRIDE + k0);
            float4 a3 = *(const float4*)(Ap + 3 * ASTRIDE + k0);
            #pragma unroll
            for (int kk = 0; kk < 4; ++kk) {
                float4 w0 = *(const float4*)(Ws + (k0 + kk) * DIMC + cg * 4);
                float4 w1 = *(const float4*)(Ws + (k0 + kk) * DIMC + 64 + cg * 4);
                float ar[4] = { ((const float*)&a0)[kk], ((const float*)&a1)[kk],
                                ((const float*)&a2)[kk], ((const float*)&a3)[kk] };
                #pragma unroll
                for (int i = 0; i < 4; ++i) {
                    acc[i][0] = fmaf(ar[i], w0.x, acc[i][0]);
                    acc[i][1] = fmaf(ar[i], w0.y, acc[i][1]);
                    acc[i][2] = fmaf(ar[i], w0.z, acc[i][2]);
                    acc[i][3] = fmaf(ar[i], w0.w, acc[i][3]);
                    acc[i][4] = fmaf(ar[i], w1.x, acc[i][4]);
                    acc[i][5] = fmaf(ar[i], w1.y, acc[i][5]);
                    acc[i][6] = fmaf(ar[i], w1.z, acc[i][6]);
                    acc[i][7] = fmaf(ar[i], w1.w, acc[i][7]);
                }
            }
        }
    }

    if (obf) {
        unsigned short* ob = (unsigned short*)out;
        #pragma unroll
        for (int i = 0; i < 4; ++i) {
            unsigned short* op = ob + (long)(row0 + rg * 4 + i) * DIMC;
            uint2 p0, p1;
            p0.x = (unsigned int)f2bf(acc[i][0]) | ((unsigned int)f2bf(acc[i][1]) << 16);
            p0.y = (unsigned int)f2bf(acc[i][2]) | ((unsigned int)f2bf(acc[i][3]) << 16);
            p1.x = (unsigned int)f2bf(acc[i][4]) | ((unsigned int)f2bf(acc[i][5]) << 16);
            p1.y = (unsigned int)f2bf(acc[i][6]) | ((unsigned int)f2bf(acc[i][7]) << 16);
            *((uint2*)(op + cg * 4))      = p0;
            *((uint2*)(op + 64 + cg * 4)) = p1;
        }
    } else {
        #pragma unroll
        for (int i = 0; i < 4; ++i) {
            float* op = out + (long)(row0 + rg * 4 + i) * DIMC;
            *((float4*)(op + cg * 4))      = make_float4(acc[i][0], acc[i][1], acc[i][2], acc[i][3]);
            *((float4*)(op + 64 + cg * 4)) = make_float4(acc[i][4], acc[i][5], acc[i][6], acc[i][7]);
        }
    }
}

// ---------------- relation projections (bf16 outputs) ----------------
__global__ __launch_bounds__(128) void rel_proj(
    const float* __restrict__ relemb, const float* __restrict__ selfrel,
    const float* __restrict__ Wq, const float* __restrict__ bq,
    const float* __restrict__ Wk, const float* __restrict__ bk,
    unsigned short* __restrict__ Qre, unsigned short* __restrict__ Kre, int R)
{
    int t = blockIdx.x;
    int c = threadIdx.x;
    const float* row = (t < R) ? (relemb + (long)t * DIMC) : selfrel;
    float aq = bq[c], ak = bk[c];
    for (int k = 0; k < DIMC; ++k) {
        float a = row[k];
        aq = fmaf(a, Wq[(long)(DIMC + k) * DIMC + c], aq);
        ak = fmaf(a, Wk[(long)(DIMC + k) * DIMC + c], ak);
    }
    Qre[(long)t * DIMC + c] = f2bf(aq);
    Kre[(long)t * DIMC + c] = f2bf(ak);
}

// ---------------- CSR build ----------------
__global__ void zero_int(int* __restrict__ p, int n) {
    int i = blockIdx.x * blockDim.x + threadIdx.x;
    if (i < n) p[i] = 0;
}

__global__ void hist_kernel(const int* __restrict__ dst, int* __restrict__ deg, int E) {
    int e = blockIdx.x * blockDim.x + threadIdx.x;
    if (e < E) atomicAdd(&deg[dst[e]], 1);
}

__global__ __launch_bounds__(256) void partial_sums(const int* __restrict__ deg,
                                                    int* __restrict__ partial, int N)
{
    __shared__ int sh[256];
    int t = threadIdx.x;
    int beg = blockIdx.x * 1024 + t * 4;
    int s = 0;
    if (beg + 3 < N) { int4 v = *(const int4*)(deg + beg); s = v.x + v.y + v.z + v.w; }
    else { for (int j = 0; j < 4; ++j) if (beg + j < N) s += deg[beg + j]; }
    sh[t] = s;
    __syncthreads();
    for (int d = 128; d >= 1; d >>= 1) {
        if (t < d) sh[t] += sh[t + d];
        __syncthreads();
    }
    if (t == 0) partial[blockIdx.x] = sh[0];
}

__global__ __launch_bounds__(256) void scan_partials(int* __restrict__ partial, int nb)
{
    __shared__ int sh[256];
    int t = threadIdx.x;
    sh[t] = (t < nb) ? partial[t] : 0;
    __syncthreads();
    for (int d = 1; d < 256; d <<= 1) {
        int v = (t >= d) ? sh[t - d] : 0;
        __syncthreads();
        sh[t] += v;
        __syncthreads();
    }
    if (t < nb) partial[t] = (t == 0) ? 0 : sh[t - 1];
}

__global__ __launch_bounds__(256) void write_offsets(const int* __restrict__ deg,
                                                     const int* __restrict__ partial,
                                                     int* __restrict__ offs,
                                                     int* __restrict__ cursor, int N)
{
    __shared__ int sh[256];
    int t = threadIdx.x;
    int beg = blockIdx.x * 1024 + t * 4;
    int d0 = 0, d1 = 0, d2 = 0, d3 = 0;
    if (beg + 3 < N) { int4 v = *(const int4*)(deg + beg); d0 = v.x; d1 = v.y; d2 = v.z; d3 = v.w; }
    else {
        if (beg < N)     d0 = deg[beg];
        if (beg + 1 < N) d1 = deg[beg + 1];
        if (beg + 2 < N) d2 = deg[beg + 2];
        if (beg + 3 < N) d3 = deg[beg + 3];
    }
    int s = d0 + d1 + d2 + d3;
    sh[t] = s;
    __syncthreads();
    for (int d = 1; d < 256; d <<= 1) {
        int v = (t >= d) ? sh[t - d] : 0;
        __syncthreads();
        sh[t] += v;
        __syncthreads();
    }
    int base = partial[blockIdx.x] + sh[t] - s;
    int o0 = base, o1 = o0 + d0, o2 = o1 + d1, o3 = o2 + d2;
    if (beg < N)     { offs[beg]     = o0; cursor[beg]     = o0; }
    if (beg + 1 < N) { offs[beg + 1] = o1; cursor[beg + 1] = o1; }
    if (beg + 2 < N) { offs[beg + 2] = o2; cursor[beg + 2] = o2; }
    if (beg + 3 < N) { offs[beg + 3] = o3; cursor[beg + 3] = o3; }
}

__global__ void scatter_kernel(const int* __restrict__ src, const int* __restrict__ dst,
                               const int* __restrict__ etype, int* __restrict__ cursor,
                               int2* __restrict__ sedge, int E)
{
    int e = blockIdx.x * blockDim.x + threadIdx.x;
    if (e < E) {
        int d = dst[e];
        int p = atomicAdd(&cursor[d], 1);
        sedge[p] = make_int2(src[e], etype[e]);
    }
}

// ---------------- per-node flash-style dual softmax + V aggregation ----------------
// one wave per node, lane owns 2 dims; bf16 K/V/Qre/Kre gathers; edge chunks of 4
__global__ __launch_bounds__(256) void node_kernel(
    const float* __restrict__ Qn,
    const unsigned short* __restrict__ Kn, const unsigned short* __restrict__ Vn,
    const unsigned short* __restrict__ Qre, const unsigned short* __restrict__ Kre,
    const int* __restrict__ offs, const int* __restrict__ deg,
    const int2* __restrict__ sedge,
    float* __restrict__ out_sta, float* __restrict__ feat_dyn,
    int N, int R)
{
    int n = (blockIdx.x * blockDim.x + threadIdx.x) >> 6;
    int lane = threadIdx.x & 63;
    if (n >= N) return;

    const float scale = 0.08838834764831845f;  // 1/sqrt(128)
    int base = offs[n];
    int dcnt = deg[n];

    float2 qn = ((const float2*)(Qn + (long)n * DIMC))[lane];

    // self-loop edge: src = n, type = R
    float2 ks = bf2f2(((const unsigned int*)(Kn + (long)n * DIMC))[lane]);
    float2 qr = bf2f2(((const unsigned int*)(Qre + (long)R * DIMC))[lane]);
    float2 kr = bf2f2(((const unsigned int*)(Kre + (long)R * DIMC))[lane]);
    float p = (qn.x + qr.x) * (ks.x + kr.x) + (qn.y + qr.y) * (ks.y + kr.y);
    #pragma unroll
    for (int m = 32; m >= 1; m >>= 1) p += __shfl_xor(p, m);
    float a_self = p * scale;

    float2 vs = bf2f2(((const unsigned int*)(Vn + (long)n * DIMC))[lane]);
    float m_dyn = a_self, s_dyn = 1.0f;
    float m_sta = -a_self, s_sta = 1.0f;
    float2 accd = vs;
    float2 accs = vs;

    int i = 0;
    for (; i + 4 <= dcnt; i += 4) {
        int2 e0 = sedge[base + i],     e1 = sedge[base + i + 1];
        int2 e2 = sedge[base + i + 2], e3 = sedge[base + i + 3];

        float2 kn0 = bf2f2(((const unsigned int*)(Kn + (long)e0.x * DIMC))[lane]);
        float2 kn1 = bf2f2(((const unsigned int*)(Kn + (long)e1.x * DIMC))[lane]);
        float2 kn2 = bf2f2(((const unsigned int*)(Kn + (long)e2.x * DIMC))[lane]);
        float2 kn3 = bf2f2(((const unsigned int*)(Kn + (long)e3.x * DIMC))[lane]);
        float2 q0 = bf2f2(((const unsigned int*)(Qre + (long)e0.y * DIMC))[lane]);
        float2 q1 = bf2f2(((const unsigned int*)(Qre + (long)e1.y * DIMC))[lane]);
        float2 q2 = bf2f2(((const unsigned int*)(Qre + (long)e2.y * DIMC))[lane]);
        float2 q3 = bf2f2(((const unsigned int*)(Qre + (long)e3.y * DIMC))[lane]);
        float2 k0 = bf2f2(((const unsigned int*)(Kre + (long)e0.y * DIMC))[lane]);
        float2 k1 = bf2f2(((const unsigned int*)(Kre + (long)e1.y * DIMC))[lane]);
        float2 k2 = bf2f2(((const unsigned int*)(Kre + (long)e2.y * DIMC))[lane]);
        float2 k3 = bf2f2(((const unsigned int*)(Kre + (long)e3.y * DIMC))[lane]);
        float2 v0 = bf2f2(((const unsigned int*)(Vn + (long)e0.x * DIMC))[lane]);
        float2 v1 = bf2f2(((const unsigned int*)(Vn + (long)e1.x * DIMC))[lane]);
        float2 v2 = bf2f2(((const unsigned int*)(Vn + (long)e2.x * DIMC))[lane]);
        float2 v3 = bf2f2(((const unsigned int*)(Vn + (long)e3.x * DIMC))[lane]);

        float p0 = (qn.x + q0.x) * (kn0.x + k0.x) + (qn.y + q0.y) * (kn0.y + k0.y);
        float p1 = (qn.x + q1.x) * (kn1.x + k1.x) + (qn.y + q1.y) * (kn1.y + k1.y);
        float p2 = (qn.x + q2.x) * (kn2.x + k2.x) + (qn.y + q2.y) * (kn2.y + k2.y);
        float p3 = (qn.x + q3.x) * (kn3.x + k3.x) + (qn.y + q3.y) * (kn3.y + k3.y);
        #pragma unroll
        for (int m = 32; m >= 1; m >>= 1) {
            p0 += __shfl_xor(p0, m);
            p1 += __shfl_xor(p1, m);
            p2 += __shfl_xor(p2, m);
            p3 += __shfl_xor(p3, m);
        }
        float a0 = p0 * scale, a1 = p1 * scale, a2 = p2 * scale, a3 = p3 * scale;

        float mx = fmaxf(fmaxf(a0, a1), fmaxf(a2, a3));
        float mn = fmaxf(m_dyn, mx);
        float f  = __expf(m_dyn - mn);
        float w0 = __expf(a0 - mn), w1 = __expf(a1 - mn);
        float w2 = __expf(a2 - mn), w3 = __expf(a3 - mn);
        s_dyn = fmaf(s_dyn, f, (w0 + w1) + (w2 + w3));
        accd.x = fmaf(accd.x, f, fmaf(w0, v0.x, fmaf(w1, v1.x, fmaf(w2, v2.x, w3 * v3.x))));
        accd.y = fmaf(accd.y, f, fmaf(w0, v0.y, fmaf(w1, v1.y, fmaf(w2, v2.y, w3 * v3.y))));
        m_dyn = mn;

        float nmx = -fminf(fminf(a0, a1), fminf(a2, a3));
        float ms = fmaxf(m_sta, nmx);
        float fs = __expf(m_sta - ms);
        float u0 = __expf(-a0 - ms), u1 = __expf(-a1 - ms);
        float u2 = __expf(-a2 - ms), u3 = __expf(-a3 - ms);
        s_sta = fmaf(s_sta, fs, (u0 + u1) + (u2 + u3));
        accs.x = fmaf(accs.x, fs, fmaf(u0, v0.x, fmaf(u1, v1.x, fmaf(u2, v2.x, u3 * v3.x))));
        accs.y = fmaf(accs.y, fs, fmaf(u0, v0.y, fmaf(u1, v1.y, fmaf(u2, v2.y, u3 * v3.y))));
        m_sta = ms;
    }

    for (; i < dcnt; ++i) {
        int2 e = sedge[base + i];
        float2 kn = bf2f2(((const unsigned int*)(Kn + (long)e.x * DIMC))[lane]);
        float2 q2 = bf2f2(((const unsigned int*)(Qre + (long)e.y * DIMC))[lane]);
        float2 k2 = bf2f2(((const unsigned int*)(Kre + (long)e.y * DIMC))[lane]);
        float pp = (qn.x + q2.x) * (kn.x + k2.x) + (qn.y + q2.y) * (kn.y + k2.y);
        #pragma unroll
        for (int m = 32; m >= 1; m >>= 1) pp += __shfl_xor(pp, m);
        float a = pp * scale;

        float2 v = bf2f2(((const unsigned int*)(Vn + (long)e.x * DIMC))[lane]);

        float mn = fmaxf(m_dyn, a);
        float fd = __expf(m_dyn - mn);
        float wd = __expf(a - mn);
        s_dyn = fmaf(s_dyn, fd, wd);
        accd.x = fmaf(accd.x, fd, wd * v.x);
        accd.y = fmaf(accd.y, fd, wd * v.y);
        m_dyn = mn;

        float ms = fmaxf(m_sta, -a);
        float fs = __expf(m_sta - ms);
        float ws_ = __expf(-a - ms);
        s_sta = fmaf(s_sta, fs, ws_);
        accs.x = fmaf(accs.x, fs, ws_ * v.x);
        accs.y = fmaf(accs.y, fs, ws_ * v.y);
        m_sta = ms;
    }

    float denom = (float)(dcnt + 1);
    float id_ = 1.0f / (s_dyn * denom);
    float is_ = 1.0f / (s_sta * denom);
    ((float2*)(out_sta + (long)n * DIMC))[lane] = make_float2(accs.x * is_, accs.y * is_);
    ((float2*)(feat_dyn + (long)n * DIMC))[lane] = make_float2(accd.x * id_, accd.y * id_);
}

// ---------------- launch ----------------
extern "C" void kernel_launch(void* const* d_in, const int* in_sizes, int n_in,
                              void* d_out, int out_size, void* d_ws, size_t ws_size,
                              hipStream_t stream)
{
    const float* curr    = (const float*)d_in[0];
    const float* last    = (const float*)d_in[1];
    const float* relemb  = (const float*)d_in[2];
    const float* selfrel = (const float*)d_in[3];
    const float* Wq      = (const float*)d_in[4];
    const float* bq      = (const float*)d_in[5];
    const float* Wk      = (const float*)d_in[6];
    const float* bk      = (const float*)d_in[7];
    const float* Wv      = (const float*)d_in[8];
    const float* bv      = (const float*)d_in[9];
    const float* dynw    = (const float*)d_in[10];
    const int*   eidx    = (const int*)d_in[11];
    const int*   etype   = (const int*)d_in[12];
    float* out = (float*)d_out;

    const int N = in_sizes[0] / DIMC;   // 40000
    const int E = in_sizes[12];         // 400000
    const int R = in_sizes[2] / DIMC;   // 502
    const int* esrc = eidx;
    const int* edst = eidx + E;

    // workspace carve-up (16B-aligned chunks)
    char* wp = (char*)d_ws;
    auto alloc = [&](size_t bytes) { char* r = wp; wp += (bytes + 15) & ~(size_t)15; return r; };
    size_t nd = (size_t)N * DIMC;
    float*          Qn    = (float*)alloc(nd * 4);
    unsigned short* Knb   = (unsigned short*)alloc(nd * 2);
    unsigned short* Vnb   = (unsigned short*)alloc(nd * 2);
    float*          Fd    = (float*)alloc(nd * 4);
    unsigned short* Qreb  = (unsigned short*)alloc((size_t)(R + 1) * DIMC * 2);
    unsigned short* Kreb  = (unsigned short*)alloc((size_t)(R + 1) * DIMC * 2);
    int*            deg   = (int*)alloc((size_t)N * 4);
    int*            offs  = (int*)alloc((size_t)N * 4);
    int*            cursor= (int*)alloc((size_t)N * 4);
    int2*           sedge = (int2*)alloc((size_t)E * 8);
    int*            partial = (int*)alloc(256 * 4);

    const int gblk = N / BM;                 // 625
    const int sblk = (N + 1023) / 1024;      // 40

    Gemm3 qkv;
    qkv.A[0] = curr;  qkv.W[0] = Wq;  qkv.bias[0] = nullptr; qkv.out[0] = Qn;           qkv.obf[0] = 0;
    qkv.A[1] = last;  qkv.W[1] = Wk;  qkv.bias[1] = nullptr; qkv.out[1] = (float*)Knb;  qkv.obf[1] = 1;
    qkv.A[2] = last;  qkv.W[2] = Wv;  qkv.bias[2] = bv;      qkv.out[2] = (float*)Vnb;  qkv.obf[2] = 1;
    hipLaunchKernelGGL(gemm_tiled_multi, dim3(gblk, 3), dim3(256), 0, stream, qkv, N);

    hipLaunchKernelGGL(rel_proj, dim3(R + 1), dim3(128), 0, stream,
                       relemb, selfrel, Wq, bq, Wk, bk, Qreb, Kreb, R);
    hipLaunchKernelGGL(zero_int, dim3((N + 255) / 256), dim3(256), 0, stream, deg, N);
    hipLaunchKernelGGL(hist_kernel, dim3((E + 255) / 256), dim3(256), 0, stream, edst, deg, E);
    hipLaunchKernelGGL(partial_sums, dim3(sblk), dim3(256), 0, stream, deg, partial, N);
    hipLaunchKernelGGL(scan_partials, dim3(1), dim3(256), 0, stream, partial, sblk);
    hipLaunchKernelGGL(write_offsets, dim3(sblk), dim3(256), 0, stream,
                       deg, partial, offs, cursor, N);
    hipLaunchKernelGGL(scatter_kernel, dim3((E + 255) / 256), dim3(256), 0, stream,
                       esrc, edst, etype, cursor, sedge, E);
    hipLaunchKernelGGL(node_kernel, dim3((N + 3) / 4), dim3(256), 0, stream,
                       Qn, Knb, Vnb, Qreb, Kreb, offs, deg, sedge, out, Fd, N, R);

    Gemm3 fin;
    fin.A[0] = Fd;  fin.W[0] = dynw; fin.bias[0] = nullptr; fin.out[0] = out + nd; fin.obf[0] = 0;
    fin.A[1] = Fd;  fin.W[1] = dynw; fin.bias[1] = nullptr; fin.out[1] = out + nd; fin.obf[1] = 0;
    fin.A[2] = Fd;  fin.W[2] = dynw; fin.bias[2] = nullptr; fin.out[2] = out + nd; fin.obf[2] = 0;
    hipLaunchKernelGGL(gemm_tiled_multi, dim3(gblk, 1), dim3(256), 0, stream, fin, N);
}

// Round 6
// 248.552 us; speedup vs baseline: 2.8859x; 1.1872x over previous
//
#include <hip/hip_runtime.h>
#include <math.h>

#define DIMC 128

typedef __attribute__((ext_vector_type(8))) short short8;
typedef __attribute__((ext_vector_type(4))) float floatx4;

// bf16 helpers (round-to-nearest-even pack, bit-shift unpack)
static __device__ __forceinline__ unsigned short f2bf(float x) {
    union { float f; unsigned int u; } v; v.f = x;
    unsigned int r = v.u + 0x7FFFu + ((v.u >> 16) & 1u);
    return (unsigned short)(r >> 16);
}
static __device__ __forceinline__ float2 bf2f2(unsigned int u) {
    union { unsigned int i; float f; } a, b;
    a.i = u << 16; b.i = u & 0xFFFF0000u;
    return make_float2(a.f, b.f);
}

// ---------------- W -> bf16 B-fragment precompute ----------------
// Fragment order: F[(t*4+s)*64 + lane] = 8 bf16, j=0..7:
//   W[s*32 + (lane>>4)*8 + j][t*16 + (lane&15)]   (W row-major [k][n], 128x128)
struct PrepArgs { const float* W[4]; unsigned short* F[4]; };

__global__ __launch_bounds__(64) void prep_wfrag(PrepArgs a)
{
    int mat = blockIdx.y;
    int ts  = blockIdx.x;            // 0..31 = t*4+s
    int s = ts & 3, t = ts >> 2;
    int lane = threadIdx.x;
    int q = lane >> 4, c = lane & 15;
    const float* W = a.W[mat];
    unsigned short o[8];
    #pragma unroll
    for (int j = 0; j < 8; ++j)
        o[j] = f2bf(W[(long)(s * 32 + q * 8 + j) * DIMC + t * 16 + c]);
    uint4 u;
    u.x = (unsigned)o[0] | ((unsigned)o[1] << 16);
    u.y = (unsigned)o[2] | ((unsigned)o[3] << 16);
    u.z = (unsigned)o[4] | ((unsigned)o[5] << 16);
    u.w = (unsigned)o[6] | ((unsigned)o[7] << 16);
    ((uint4*)a.F[mat])[ts * 64 + lane] = u;
}

// ---------------- MFMA GEMM: out[M,128] = A[M,128] @ W[128,128] (+bias) ----------------
// block = 256 thr (4 waves); wave handles 16 rows x 128 cols = 8 tiles of 16x16, K=128.
// W fragments live in registers (32 x short8). A: f32 (converted) or bf16.
// Output: f32 or bf16 (lane-paired pack).
struct GemmM3 {
    const float*          Af[3];   // f32 A or null
    const unsigned short* Ab[3];   // bf16 A or null
    const unsigned short* F[3];    // fragment-ordered W (bf16)
    const float*          bias[3];
    float*                outf[3]; // f32 out or null
    unsigned short*       outb[3]; // bf16 out or null
};

__global__ __launch_bounds__(256) void gemm_mfma(GemmM3 g, int M)
{
    const int which = blockIdx.y;
    const float*          __restrict__ Af   = g.Af[which];
    const unsigned short* __restrict__ Ab   = g.Ab[which];
    const unsigned short* __restrict__ F    = g.F[which];
    const float*          __restrict__ bias = g.bias[which];
    float*          __restrict__ outf = g.outf[which];
    unsigned short* __restrict__ outb = g.outb[which];

    const int wave = threadIdx.x >> 6;
    const int lane = threadIdx.x & 63;
    const int q = lane >> 4, c = lane & 15;
    const int rowbase = blockIdx.x * 64 + wave * 16;

    // W fragments -> registers
    short8 wf[8][4];
    const uint4* Fp = (const uint4*)F;
    #pragma unroll
    for (int t = 0; t < 8; ++t)
        #pragma unroll
        for (int s = 0; s < 4; ++s) {
            uint4 u = Fp[(t * 4 + s) * 64 + lane];
            wf[t][s] = *(short8*)&u;
        }

    floatx4 acc[8];
    #pragma unroll
    for (int t = 0; t < 8; ++t) {
        float b = bias ? bias[t * 16 + c] : 0.0f;
        acc[t] = (floatx4){b, b, b, b};
    }

    // A fragments: row = rowbase + c, k = s*32 + q*8 + j
    short8 af[4];
    if (Af) {
        const float* Ar = Af + (long)(rowbase + c) * DIMC + q * 8;
        #pragma unroll
        for (int s = 0; s < 4; ++s) {
            float4 x0 = *(const float4*)(Ar + s * 32);
            float4 x1 = *(const float4*)(Ar + s * 32 + 4);
            uint4 u;
            u.x = (unsigned)f2bf(x0.x) | ((unsigned)f2bf(x0.y) << 16);
            u.y = (unsigned)f2bf(x0.z) | ((unsigned)f2bf(x0.w) << 16);
            u.z = (unsigned)f2bf(x1.x) | ((unsigned)f2bf(x1.y) << 16);
            u.w = (unsigned)f2bf(x1.z) | ((unsigned)f2bf(x1.w) << 16);
            af[s] = *(short8*)&u;
        }
    } else {
        const unsigned short* Ar = Ab + (long)(rowbase + c) * DIMC + q * 8;
        #pragma unroll
        for (int s = 0; s < 4; ++s) {
            uint4 u = *(const uint4*)(Ar + s * 32);
            af[s] = *(short8*)&u;
        }
    }

    #pragma unroll
    for (int t = 0; t < 8; ++t)
        #pragma unroll
        for (int s = 0; s < 4; ++s)
            acc[t] = __builtin_amdgcn_mfma_f32_16x16x32_bf16(af[s], wf[t][s], acc[t], 0, 0, 0);

    // epilogue: C/D layout col = t*16 + c, row = rowbase + q*4 + r
    if (outf) {
        #pragma unroll
        for (int t = 0; t < 8; ++t)
            #pragma unroll
            for (int r = 0; r < 4; ++r)
                outf[(long)(rowbase + q * 4 + r) * DIMC + t * 16 + c] = acc[t][r];
    } else {
        #pragma unroll
        for (int t = 0; t < 8; ++t)
            #pragma unroll
            for (int r = 0; r < 4; ++r) {
                unsigned int u = f2bf(acc[t][r]);
                unsigned int o = (unsigned int)__shfl_xor((int)u, 1);
                if ((lane & 1) == 0) {
                    unsigned int word = u | (o << 16);
                    ((unsigned int*)outb)[(long)(rowbase + q * 4 + r) * 64 + t * 8 + (c >> 1)] = word;
                }
            }
    }
}

// ---------------- relation projections (f32 compute, bf16 outputs) ----------------
__global__ __launch_bounds__(128) void rel_proj(
    const float* __restrict__ relemb, const float* __restrict__ selfrel,
    const float* __restrict__ Wq, const float* __restrict__ bq,
    const float* __restrict__ Wk, const float* __restrict__ bk,
    unsigned short* __restrict__ Qre, unsigned short* __restrict__ Kre, int R)
{
    int t = blockIdx.x;
    int c = threadIdx.x;
    const float* row = (t < R) ? (relemb + (long)t * DIMC) : selfrel;
    float aq = bq[c], ak = bk[c];
    for (int k = 0; k < DIMC; ++k) {
        float a = row[k];
        aq = fmaf(a, Wq[(long)(DIMC + k) * DIMC + c], aq);
        ak = fmaf(a, Wk[(long)(DIMC + k) * DIMC + c], ak);
    }
    Qre[(long)t * DIMC + c] = f2bf(aq);
    Kre[(long)t * DIMC + c] = f2bf(ak);
}

// ---------------- CSR build ----------------
__global__ void zero_int(int* __restrict__ p, int n) {
    int i = blockIdx.x * blockDim.x + threadIdx.x;
    if (i < n) p[i] = 0;
}

__global__ void hist_kernel(const int* __restrict__ dst, int* __restrict__ deg, int E) {
    int e = blockIdx.x * blockDim.x + threadIdx.x;
    if (e < E) atomicAdd(&deg[dst[e]], 1);
}

__global__ __launch_bounds__(256) void partial_sums(const int* __restrict__ deg,
                                                    int* __restrict__ partial, int N)
{
    __shared__ int sh[256];
    int t = threadIdx.x;
    int beg = blockIdx.x * 1024 + t * 4;
    int s = 0;
    if (beg + 3 < N) { int4 v = *(const int4*)(deg + beg); s = v.x + v.y + v.z + v.w; }
    else { for (int j = 0; j < 4; ++j) if (beg + j < N) s += deg[beg + j]; }
    sh[t] = s;
    __syncthreads();
    for (int d = 128; d >= 1; d >>= 1) {
        if (t < d) sh[t] += sh[t + d];
        __syncthreads();
    }
    if (t == 0) partial[blockIdx.x] = sh[0];
}

__global__ __launch_bounds__(256) void scan_partials(int* __restrict__ partial, int nb)
{
    __shared__ int sh[256];
    int t = threadIdx.x;
    sh[t] = (t < nb) ? partial[t] : 0;
    __syncthreads();
    for (int d = 1; d < 256; d <<= 1) {
        int v = (t >= d) ? sh[t - d] : 0;
        __syncthreads();
        sh[t] += v;
        __syncthreads();
    }
    if (t < nb) partial[t] = (t == 0) ? 0 : sh[t - 1];
}

__global__ __launch_bounds__(256) void write_offsets(const int* __restrict__ deg,
                                                     const int* __restrict__ partial,
                                                     int* __restrict__ offs,
                                                     int* __restrict__ cursor, int N)
{
    __shared__ int sh[256];
    int t = threadIdx.x;
    int beg = blockIdx.x * 1024 + t * 4;
    int d0 = 0, d1 = 0, d2 = 0, d3 = 0;
    if (beg + 3 < N) { int4 v = *(const int4*)(deg + beg); d0 = v.x; d1 = v.y; d2 = v.z; d3 = v.w; }
    else {
        if (beg < N)     d0 = deg[beg];
        if (beg + 1 < N) d1 = deg[beg + 1];
        if (beg + 2 < N) d2 = deg[beg + 2];
        if (beg + 3 < N) d3 = deg[beg + 3];
    }
    int s = d0 + d1 + d2 + d3;
    sh[t] = s;
    __syncthreads();
    for (int d = 1; d < 256; d <<= 1) {
        int v = (t >= d) ? sh[t - d] : 0;
        __syncthreads();
        sh[t] += v;
        __syncthreads();
    }
    int base = partial[blockIdx.x] + sh[t] - s;
    int o0 = base, o1 = o0 + d0, o2 = o1 + d1, o3 = o2 + d2;
    if (beg < N)     { offs[beg]     = o0; cursor[beg]     = o0; }
    if (beg + 1 < N) { offs[beg + 1] = o1; cursor[beg + 1] = o1; }
    if (beg + 2 < N) { offs[beg + 2] = o2; cursor[beg + 2] = o2; }
    if (beg + 3 < N) { offs[beg + 3] = o3; cursor[beg + 3] = o3; }
}

__global__ void scatter_kernel(const int* __restrict__ src, const int* __restrict__ dst,
                               const int* __restrict__ etype, int* __restrict__ cursor,
                               int2* __restrict__ sedge, int E)
{
    int e = blockIdx.x * blockDim.x + threadIdx.x;
    if (e < E) {
        int d = dst[e];
        int p = atomicAdd(&cursor[d], 1);
        sedge[p] = make_int2(src[e], etype[e]);
    }
}

// ---------------- per-node flash-style dual softmax + V aggregation ----------------
// one wave per node, lane owns 2 dims; bf16 K/V/Qre/Kre gathers; edge chunks of 4
__global__ __launch_bounds__(256) void node_kernel(
    const float* __restrict__ Qn,
    const unsigned short* __restrict__ Kn, const unsigned short* __restrict__ Vn,
    const unsigned short* __restrict__ Qre, const unsigned short* __restrict__ Kre,
    const int* __restrict__ offs, const int* __restrict__ deg,
    const int2* __restrict__ sedge,
    float* __restrict__ out_sta, unsigned short* __restrict__ feat_dyn,
    int N, int R)
{
    int n = (blockIdx.x * blockDim.x + threadIdx.x) >> 6;
    int lane = threadIdx.x & 63;
    if (n >= N) return;

    const float scale = 0.08838834764831845f;  // 1/sqrt(128)
    int base = offs[n];
    int dcnt = deg[n];

    float2 qn = ((const float2*)(Qn + (long)n * DIMC))[lane];

    // self-loop edge: src = n, type = R
    float2 ks = bf2f2(((const unsigned int*)(Kn + (long)n * DIMC))[lane]);
    float2 qr = bf2f2(((const unsigned int*)(Qre + (long)R * DIMC))[lane]);
    float2 kr = bf2f2(((const unsigned int*)(Kre + (long)R * DIMC))[lane]);
    float p = (qn.x + qr.x) * (ks.x + kr.x) + (qn.y + qr.y) * (ks.y + kr.y);
    #pragma unroll
    for (int m = 32; m >= 1; m >>= 1) p += __shfl_xor(p, m);
    float a_self = p * scale;

    float2 vs = bf2f2(((const unsigned int*)(Vn + (long)n * DIMC))[lane]);
    float m_dyn = a_self, s_dyn = 1.0f;
    float m_sta = -a_self, s_sta = 1.0f;
    float2 accd = vs;
    float2 accs = vs;

    int i = 0;
    for (; i + 4 <= dcnt; i += 4) {
        int2 e0 = sedge[base + i],     e1 = sedge[base + i + 1];
        int2 e2 = sedge[base + i + 2], e3 = sedge[base + i + 3];

        float2 kn0 = bf2f2(((const unsigned int*)(Kn + (long)e0.x * DIMC))[lane]);
        float2 kn1 = bf2f2(((const unsigned int*)(Kn + (long)e1.x * DIMC))[lane]);
        float2 kn2 = bf2f2(((const unsigned int*)(Kn + (long)e2.x * DIMC))[lane]);
        float2 kn3 = bf2f2(((const unsigned int*)(Kn + (long)e3.x * DIMC))[lane]);
        float2 q0 = bf2f2(((const unsigned int*)(Qre + (long)e0.y * DIMC))[lane]);
        float2 q1 = bf2f2(((const unsigned int*)(Qre + (long)e1.y * DIMC))[lane]);
        float2 q2 = bf2f2(((const unsigned int*)(Qre + (long)e2.y * DIMC))[lane]);
        float2 q3 = bf2f2(((const unsigned int*)(Qre + (long)e3.y * DIMC))[lane]);
        float2 k0 = bf2f2(((const unsigned int*)(Kre + (long)e0.y * DIMC))[lane]);
        float2 k1 = bf2f2(((const unsigned int*)(Kre + (long)e1.y * DIMC))[lane]);
        float2 k2 = bf2f2(((const unsigned int*)(Kre + (long)e2.y * DIMC))[lane]);
        float2 k3 = bf2f2(((const unsigned int*)(Kre + (long)e3.y * DIMC))[lane]);
        float2 v0 = bf2f2(((const unsigned int*)(Vn + (long)e0.x * DIMC))[lane]);
        float2 v1 = bf2f2(((const unsigned int*)(Vn + (long)e1.x * DIMC))[lane]);
        float2 v2 = bf2f2(((const unsigned int*)(Vn + (long)e2.x * DIMC))[lane]);
        float2 v3 = bf2f2(((const unsigned int*)(Vn + (long)e3.x * DIMC))[lane]);

        float p0 = (qn.x + q0.x) * (kn0.x + k0.x) + (qn.y + q0.y) * (kn0.y + k0.y);
        float p1 = (qn.x + q1.x) * (kn1.x + k1.x) + (qn.y + q1.y) * (kn1.y + k1.y);
        float p2 = (qn.x + q2.x) * (kn2.x + k2.x) + (qn.y + q2.y) * (kn2.y + k2.y);
        float p3 = (qn.x + q3.x) * (kn3.x + k3.x) + (qn.y + q3.y) * (kn3.y + k3.y);
        #pragma unroll
        for (int m = 32; m >= 1; m >>= 1) {
            p0 += __shfl_xor(p0, m);
            p1 += __shfl_xor(p1, m);
            p2 += __shfl_xor(p2, m);
            p3 += __shfl_xor(p3, m);
        }
        float a0 = p0 * scale, a1 = p1 * scale, a2 = p2 * scale, a3 = p3 * scale;

        float mx = fmaxf(fmaxf(a0, a1), fmaxf(a2, a3));
        float mn = fmaxf(m_dyn, mx);
        float f  = __expf(m_dyn - mn);
        float w0 = __expf(a0 - mn), w1 = __expf(a1 - mn);
        float w2 = __expf(a2 - mn), w3 = __expf(a3 - mn);
        s_dyn = fmaf(s_dyn, f, (w0 + w1) + (w2 + w3));
        accd.x = fmaf(accd.x, f, fmaf(w0, v0.x, fmaf(w1, v1.x, fmaf(w2, v2.x, w3 * v3.x))));
        accd.y = fmaf(accd.y, f, fmaf(w0, v0.y, fmaf(w1, v1.y, fmaf(w2, v2.y, w3 * v3.y))));
        m_dyn = mn;

        float nmx = -fminf(fminf(a0, a1), fminf(a2, a3));
        float ms = fmaxf(m_sta, nmx);
        float fs = __expf(m_sta - ms);
        float u0 = __expf(-a0 - ms), u1 = __expf(-a1 - ms);
        float u2 = __expf(-a2 - ms), u3 = __expf(-a3 - ms);
        s_sta = fmaf(s_sta, fs, (u0 + u1) + (u2 + u3));
        accs.x = fmaf(accs.x, fs, fmaf(u0, v0.x, fmaf(u1, v1.x, fmaf(u2, v2.x, u3 * v3.x))));
        accs.y = fmaf(accs.y, fs, fmaf(u0, v0.y, fmaf(u1, v1.y, fmaf(u2, v2.y, u3 * v3.y))));
        m_sta = ms;
    }

    for (; i < dcnt; ++i) {
        int2 e = sedge[base + i];
        float2 kn = bf2f2(((const unsigned int*)(Kn + (long)e.x * DIMC))[lane]);
        float2 q2 = bf2f2(((const unsigned int*)(Qre + (long)e.y * DIMC))[lane]);
        float2 k2 = bf2f2(((const unsigned int*)(Kre + (long)e.y * DIMC))[lane]);
        float pp = (qn.x + q2.x) * (kn.x + k2.x) + (qn.y + q2.y) * (kn.y + k2.y);
        #pragma unroll
        for (int m = 32; m >= 1; m >>= 1) pp += __shfl_xor(pp, m);
        float a = pp * scale;

        float2 v = bf2f2(((const unsigned int*)(Vn + (long)e.x * DIMC))[lane]);

        float mn = fmaxf(m_dyn, a);
        float fd = __expf(m_dyn - mn);
        float wd = __expf(a - mn);
        s_dyn = fmaf(s_dyn, fd, wd);
        accd.x = fmaf(accd.x, fd, wd * v.x);
        accd.y = fmaf(accd.y, fd, wd * v.y);
        m_dyn = mn;

        float ms = fmaxf(m_sta, -a);
        float fs = __expf(m_sta - ms);
        float ws_ = __expf(-a - ms);
        s_sta = fmaf(s_sta, fs, ws_);
        accs.x = fmaf(accs.x, fs, ws_ * v.x);
        accs.y = fmaf(accs.y, fs, ws_ * v.y);
        m_sta = ms;
    }

    float denom = (float)(dcnt + 1);
    float id_ = 1.0f / (s_dyn * denom);
    float is_ = 1.0f / (s_sta * denom);
    ((float2*)(out_sta + (long)n * DIMC))[lane] = make_float2(accs.x * is_, accs.y * is_);
    unsigned int pd = (unsigned)f2bf(accd.x * id_) | ((unsigned)f2bf(accd.y * id_) << 16);
    ((unsigned int*)feat_dyn)[(long)n * 64 + lane] = pd;
}

// ---------------- launch ----------------
extern "C" void kernel_launch(void* const* d_in, const int* in_sizes, int n_in,
                              void* d_out, int out_size, void* d_ws, size_t ws_size,
                              hipStream_t stream)
{
    const float* curr    = (const float*)d_in[0];
    const float* last    = (const float*)d_in[1];
    const float* relemb  = (const float*)d_in[2];
    const float* selfrel = (const float*)d_in[3];
    const float* Wq      = (const float*)d_in[4];
    const float* bq      = (const float*)d_in[5];
    const float* Wk      = (const float*)d_in[6];
    const float* bk      = (const float*)d_in[7];
    const float* Wv      = (const float*)d_in[8];
    const float* bv      = (const float*)d_in[9];
    const float* dynw    = (const float*)d_in[10];
    const int*   eidx    = (const int*)d_in[11];
    const int*   etype   = (const int*)d_in[12];
    float* out = (float*)d_out;

    const int N = in_sizes[0] / DIMC;   // 40000
    const int E = in_sizes[12];         // 400000
    const int R = in_sizes[2] / DIMC;   // 502
    const int* esrc = eidx;
    const int* edst = eidx + E;

    // workspace carve-up (16B-aligned chunks)
    char* wp = (char*)d_ws;
    auto alloc = [&](size_t bytes) { char* r = wp; wp += (bytes + 15) & ~(size_t)15; return r; };
    size_t nd = (size_t)N * DIMC;
    float*          Qn    = (float*)alloc(nd * 4);
    unsigned short* Knb   = (unsigned short*)alloc(nd * 2);
    unsigned short* Vnb   = (unsigned short*)alloc(nd * 2);
    unsigned short* Fdb   = (unsigned short*)alloc(nd * 2);
    unsigned short* Qreb  = (unsigned short*)alloc((size_t)(R + 1) * DIMC * 2);
    unsigned short* Kreb  = (unsigned short*)alloc((size_t)(R + 1) * DIMC * 2);
    unsigned short* FWq   = (unsigned short*)alloc(2048 * 8 * 2);   // 32 frag x 64 lane x 8 bf16
    unsigned short* FWk   = (unsigned short*)alloc(2048 * 8 * 2);
    unsigned short* FWv   = (unsigned short*)alloc(2048 * 8 * 2);
    unsigned short* FWd   = (unsigned short*)alloc(2048 * 8 * 2);
    int*            deg   = (int*)alloc((size_t)N * 4);
    int*            offs  = (int*)alloc((size_t)N * 4);
    int*            cursor= (int*)alloc((size_t)N * 4);
    int2*           sedge = (int2*)alloc((size_t)E * 8);
    int*            partial = (int*)alloc(256 * 4);

    const int gblk = N / 64;                 // 625
    const int sblk = (N + 1023) / 1024;      // 40

    PrepArgs pa;
    pa.W[0] = Wq;   pa.F[0] = FWq;
    pa.W[1] = Wk;   pa.F[1] = FWk;
    pa.W[2] = Wv;   pa.F[2] = FWv;
    pa.W[3] = dynw; pa.F[3] = FWd;
    hipLaunchKernelGGL(prep_wfrag, dim3(32, 4), dim3(64), 0, stream, pa);

    GemmM3 qkv;
    qkv.Af[0] = curr; qkv.Ab[0] = nullptr; qkv.F[0] = FWq; qkv.bias[0] = nullptr; qkv.outf[0] = Qn;      qkv.outb[0] = nullptr;
    qkv.Af[1] = last; qkv.Ab[1] = nullptr; qkv.F[1] = FWk; qkv.bias[1] = nullptr; qkv.outf[1] = nullptr; qkv.outb[1] = Knb;
    qkv.Af[2] = last; qkv.Ab[2] = nullptr; qkv.F[2] = FWv; qkv.bias[2] = bv;      qkv.outf[2] = nullptr; qkv.outb[2] = Vnb;
    hipLaunchKernelGGL(gemm_mfma, dim3(gblk, 3), dim3(256), 0, stream, qkv, N);

    hipLaunchKernelGGL(rel_proj, dim3(R + 1), dim3(128), 0, stream,
                       relemb, selfrel, Wq, bq, Wk, bk, Qreb, Kreb, R);
    hipLaunchKernelGGL(zero_int, dim3((N + 255) / 256), dim3(256), 0, stream, deg, N);
    hipLaunchKernelGGL(hist_kernel, dim3((E + 255) / 256), dim3(256), 0, stream, edst, deg, E);
    hipLaunchKernelGGL(partial_sums, dim3(sblk), dim3(256), 0, stream, deg, partial, N);
    hipLaunchKernelGGL(scan_partials, dim3(1), dim3(256), 0, stream, partial, sblk);
    hipLaunchKernelGGL(write_offsets, dim3(sblk), dim3(256), 0, stream,
                       deg, partial, offs, cursor, N);
    hipLaunchKernelGGL(scatter_kernel, dim3((E + 255) / 256), dim3(256), 0, stream,
                       esrc, edst, etype, cursor, sedge, E);
    hipLaunchKernelGGL(node_kernel, dim3((N + 3) / 4), dim3(256), 0, stream,
                       Qn, Knb, Vnb, Qreb, Kreb, offs, deg, sedge, out, Fdb, N, R);

    GemmM3 fin;
    fin.Af[0] = nullptr; fin.Ab[0] = Fdb; fin.F[0] = FWd; fin.bias[0] = nullptr; fin.outf[0] = out + nd; fin.outb[0] = nullptr;
    fin.Af[1] = nullptr; fin.Ab[1] = Fdb; fin.F[1] = FWd; fin.bias[1] = nullptr; fin.outf[1] = out + nd; fin.outb[1] = nullptr;
    fin.Af[2] = nullptr; fin.Ab[2] = Fdb; fin.F[2] = FWd; fin.bias[2] = nullptr; fin.outf[2] = out + nd; fin.outb[2] = nullptr;
    hipLaunchKernelGGL(gemm_mfma, dim3(gblk, 1), dim3(256), 0, stream, fin, N);
}

// Round 7
// 243.005 us; speedup vs baseline: 2.9517x; 1.0228x over previous
//
#include <hip/hip_runtime.h>
#include <hip/hip_bf16.h>
#include <math.h>

#define DIMC 128

typedef __attribute__((ext_vector_type(8))) short short8;
typedef __attribute__((ext_vector_type(4))) float floatx4;

// bf16 helpers
static __device__ __forceinline__ unsigned pk2(float lo, float hi) {
    __hip_bfloat162 h = __float22bfloat162_rn(make_float2(lo, hi));  // v_cvt_pk_bf16_f32
    return *(unsigned*)&h;
}
static __device__ __forceinline__ unsigned short f2bf(float x) {
    union { float f; unsigned int u; } v; v.f = x;
    unsigned int r = v.u + 0x7FFFu + ((v.u >> 16) & 1u);
    return (unsigned short)(r >> 16);
}
static __device__ __forceinline__ float2 bf2f2(unsigned int u) {
    union { unsigned int i; float f; } a, b;
    a.i = u << 16; b.i = u & 0xFFFF0000u;
    return make_float2(a.f, b.f);
}

// ---------------- W -> bf16 B-fragment precompute ----------------
// F[(t*4+s)*64 + lane] = 8 bf16: W[s*32 + (lane>>4)*8 + j][t*16 + (lane&15)]
struct PrepArgs { const float* W[4]; unsigned short* F[4]; };

__global__ __launch_bounds__(64) void prep_wfrag(PrepArgs a)
{
    int mat = blockIdx.y;
    int ts  = blockIdx.x;            // 0..31 = t*4+s
    int s = ts & 3, t = ts >> 2;
    int lane = threadIdx.x;
    int q = lane >> 4, c = lane & 15;
    const float* W = a.W[mat];
    unsigned short o[8];
    #pragma unroll
    for (int j = 0; j < 8; ++j)
        o[j] = f2bf(W[(long)(s * 32 + q * 8 + j) * DIMC + t * 16 + c]);
    uint4 u;
    u.x = (unsigned)o[0] | ((unsigned)o[1] << 16);
    u.y = (unsigned)o[2] | ((unsigned)o[3] << 16);
    u.z = (unsigned)o[4] | ((unsigned)o[5] << 16);
    u.w = (unsigned)o[6] | ((unsigned)o[7] << 16);
    ((uint4*)a.F[mat])[ts * 64 + lane] = u;
}

// ---------------- MFMA GEMM: out[M,128] = A[M,128] @ W[128,128] (+bias) ----------------
// wave = 16 rows x 128 cols, K=128, W fragments in registers.
// bf16 output supports stride/offset for interleaved KV writes.
struct GemmM3 {
    const float*          Af[3];
    const unsigned short* Ab[3];
    const unsigned short* F[3];
    const float*          bias[3];
    float*                outf[3];
    unsigned short*       outb[3];
    int                   ostride[3];
    int                   ooff[3];
};

__global__ __launch_bounds__(256) void gemm_mfma(GemmM3 g, int M)
{
    const int which = blockIdx.y;
    const float*          __restrict__ Af   = g.Af[which];
    const unsigned short* __restrict__ Ab   = g.Ab[which];
    const unsigned short* __restrict__ F    = g.F[which];
    const float*          __restrict__ bias = g.bias[which];
    float*          __restrict__ outf = g.outf[which];
    unsigned short* __restrict__ outb = g.outb[which];
    const int ostride = g.ostride[which];
    const int ooff    = g.ooff[which];

    const int wave = threadIdx.x >> 6;
    const int lane = threadIdx.x & 63;
    const int q = lane >> 4, c = lane & 15;
    const int rowbase = blockIdx.x * 64 + wave * 16;

    short8 wf[8][4];
    const uint4* Fp = (const uint4*)F;
    #pragma unroll
    for (int t = 0; t < 8; ++t)
        #pragma unroll
        for (int s = 0; s < 4; ++s) {
            uint4 u = Fp[(t * 4 + s) * 64 + lane];
            wf[t][s] = *(short8*)&u;
        }

    floatx4 acc[8];
    #pragma unroll
    for (int t = 0; t < 8; ++t) {
        float b = bias ? bias[t * 16 + c] : 0.0f;
        acc[t] = (floatx4){b, b, b, b};
    }

    short8 af[4];
    if (Af) {
        const float* Ar = Af + (long)(rowbase + c) * DIMC + q * 8;
        #pragma unroll
        for (int s = 0; s < 4; ++s) {
            float4 x0 = *(const float4*)(Ar + s * 32);
            float4 x1 = *(const float4*)(Ar + s * 32 + 4);
            uint4 u;
            u.x = pk2(x0.x, x0.y);
            u.y = pk2(x0.z, x0.w);
            u.z = pk2(x1.x, x1.y);
            u.w = pk2(x1.z, x1.w);
            af[s] = *(short8*)&u;
        }
    } else {
        const unsigned short* Ar = Ab + (long)(rowbase + c) * DIMC + q * 8;
        #pragma unroll
        for (int s = 0; s < 4; ++s) {
            uint4 u = *(const uint4*)(Ar + s * 32);
            af[s] = *(short8*)&u;
        }
    }

    #pragma unroll
    for (int t = 0; t < 8; ++t)
        #pragma unroll
        for (int s = 0; s < 4; ++s)
            acc[t] = __builtin_amdgcn_mfma_f32_16x16x32_bf16(af[s], wf[t][s], acc[t], 0, 0, 0);

    // epilogue: C/D layout col = t*16 + c, row = rowbase + q*4 + r
    if (outf) {
        #pragma unroll
        for (int t = 0; t < 8; ++t)
            #pragma unroll
            for (int r = 0; r < 4; ++r)
                outf[(long)(rowbase + q * 4 + r) * DIMC + t * 16 + c] = acc[t][r];
    } else {
        #pragma unroll
        for (int t = 0; t < 8; ++t)
            #pragma unroll
            for (int r = 0; r < 4; ++r) {
                float other = __shfl_xor(acc[t][r], 1);
                if ((lane & 1) == 0) {
                    unsigned word = pk2(acc[t][r], other);
                    ((unsigned*)outb)[((long)(rowbase + q * 4 + r) * 64 + t * 8 + (c >> 1))
                                      * (long)ostride + ooff] = word;
                }
            }
    }
}

// ---------------- relation projections -> interleaved QKre pairs ----------------
// QKre[t*64 + lp] = { bf16x2(qre col 2lp,2lp+1), bf16x2(kre col 2lp,2lp+1) }
__global__ __launch_bounds__(128) void rel_proj(
    const float* __restrict__ relemb, const float* __restrict__ selfrel,
    const float* __restrict__ Wq, const float* __restrict__ bq,
    const float* __restrict__ Wk, const float* __restrict__ bk,
    uint2* __restrict__ QKre, int R)
{
    int t = blockIdx.x;
    int c = threadIdx.x;
    const float* row = (t < R) ? (relemb + (long)t * DIMC) : selfrel;
    float aq = bq[c], ak = bk[c];
    for (int k = 0; k < DIMC; ++k) {
        float a = row[k];
        aq = fmaf(a, Wq[(long)(DIMC + k) * DIMC + c], aq);
        ak = fmaf(a, Wk[(long)(DIMC + k) * DIMC + c], ak);
    }
    float aqo = __shfl_xor(aq, 1);
    float ako = __shfl_xor(ak, 1);
    if ((c & 1) == 0)
        QKre[(long)t * 64 + (c >> 1)] = make_uint2(pk2(aq, aqo), pk2(ak, ako));
}

// ---------------- CSR build ----------------
__global__ void zero_int(int* __restrict__ p, int n) {
    int i = blockIdx.x * blockDim.x + threadIdx.x;
    if (i < n) p[i] = 0;
}

__global__ void hist_kernel(const int* __restrict__ dst, int* __restrict__ deg, int E) {
    int e = blockIdx.x * blockDim.x + threadIdx.x;
    if (e < E) atomicAdd(&deg[dst[e]], 1);
}

__global__ __launch_bounds__(256) void partial_sums(const int* __restrict__ deg,
                                                    int* __restrict__ partial, int N)
{
    __shared__ int sh[256];
    int t = threadIdx.x;
    int beg = blockIdx.x * 1024 + t * 4;
    int s = 0;
    if (beg + 3 < N) { int4 v = *(const int4*)(deg + beg); s = v.x + v.y + v.z + v.w; }
    else { for (int j = 0; j < 4; ++j) if (beg + j < N) s += deg[beg + j]; }
    sh[t] = s;
    __syncthreads();
    for (int d = 128; d >= 1; d >>= 1) {
        if (t < d) sh[t] += sh[t + d];
        __syncthreads();
    }
    if (t == 0) partial[blockIdx.x] = sh[0];
}

__global__ __launch_bounds__(256) void scan_partials(int* __restrict__ partial, int nb)
{
    __shared__ int sh[256];
    int t = threadIdx.x;
    sh[t] = (t < nb) ? partial[t] : 0;
    __syncthreads();
    for (int d = 1; d < 256; d <<= 1) {
        int v = (t >= d) ? sh[t - d] : 0;
        __syncthreads();
        sh[t] += v;
        __syncthreads();
    }
    if (t < nb) partial[t] = (t == 0) ? 0 : sh[t - 1];
}

__global__ __launch_bounds__(256) void write_offsets(const int* __restrict__ deg,
                                                     const int* __restrict__ partial,
                                                     int* __restrict__ offs,
                                                     int* __restrict__ cursor, int N)
{
    __shared__ int sh[256];
    int t = threadIdx.x;
    int beg = blockIdx.x * 1024 + t * 4;
    int d0 = 0, d1 = 0, d2 = 0, d3 = 0;
    if (beg + 3 < N) { int4 v = *(const int4*)(deg + beg); d0 = v.x; d1 = v.y; d2 = v.z; d3 = v.w; }
    else {
        if (beg < N)     d0 = deg[beg];
        if (beg + 1 < N) d1 = deg[beg + 1];
        if (beg + 2 < N) d2 = deg[beg + 2];
        if (beg + 3 < N) d3 = deg[beg + 3];
    }
    int s = d0 + d1 + d2 + d3;
    sh[t] = s;
    __syncthreads();
    for (int d = 1; d < 256; d <<= 1) {
        int v = (t >= d) ? sh[t - d] : 0;
        __syncthreads();
        sh[t] += v;
        __syncthreads();
    }
    int base = partial[blockIdx.x] + sh[t] - s;
    int o0 = base, o1 = o0 + d0, o2 = o1 + d1, o3 = o2 + d2;
    if (beg < N)     { offs[beg]     = o0; cursor[beg]     = o0; }
    if (beg + 1 < N) { offs[beg + 1] = o1; cursor[beg + 1] = o1; }
    if (beg + 2 < N) { offs[beg + 2] = o2; cursor[beg + 2] = o2; }
    if (beg + 3 < N) { offs[beg + 3] = o3; cursor[beg + 3] = o3; }
}

__global__ void scatter_kernel(const int* __restrict__ src, const int* __restrict__ dst,
                               const int* __restrict__ etype, int* __restrict__ cursor,
                               int2* __restrict__ sedge, int E)
{
    int e = blockIdx.x * blockDim.x + threadIdx.x;
    if (e < E) {
        int d = dst[e];
        int p = atomicAdd(&cursor[d], 1);
        sedge[p] = make_int2(src[e], etype[e]);
    }
}

// ---------------- per-node flash-style dual softmax + V aggregation ----------------
// one wave per node; interleaved KV / QKre gathers (one uint2 per edge-table each);
// base-2 online softmax (log2e folded into scale)
__global__ __launch_bounds__(256) void node_kernel(
    const float* __restrict__ Qn,
    const uint2* __restrict__ KV,     // [n*64 + lane] = {K pair, V pair}
    const uint2* __restrict__ QKre,   // [t*64 + lane] = {Qre pair, Kre pair}
    const int* __restrict__ offs, const int* __restrict__ deg,
    const int2* __restrict__ sedge,
    float* __restrict__ out_sta, unsigned* __restrict__ feat_dyn,
    int N, int R)
{
    int n = (blockIdx.x * blockDim.x + threadIdx.x) >> 6;
    int lane = threadIdx.x & 63;
    if (n >= N) return;

    const float cs = 0.08838834764831845f * 1.4426950408889634f;  // (1/sqrt(128))*log2(e)
    int base = offs[n];
    int dcnt = deg[n];

    float2 qn = ((const float2*)(Qn + (long)n * DIMC))[lane];

    // self-loop edge: src = n, type = R
    uint2 kvs = KV[(unsigned)n * 64u + lane];
    uint2 qks = QKre[(unsigned)R * 64u + lane];
    float2 ks = bf2f2(kvs.x), vs = bf2f2(kvs.y);
    float2 qr = bf2f2(qks.x), kr = bf2f2(qks.y);
    float p = (qn.x + qr.x) * (ks.x + kr.x) + (qn.y + qr.y) * (ks.y + kr.y);
    #pragma unroll
    for (int m = 32; m >= 1; m >>= 1) p += __shfl_xor(p, m);
    float a_self = p * cs;

    float m_dyn = a_self, s_dyn = 1.0f;
    float m_sta = -a_self, s_sta = 1.0f;
    float2 accd = vs;
    float2 accs = vs;

    int i = 0;
    for (; i + 4 <= dcnt; i += 4) {
        int2 e0 = sedge[base + i],     e1 = sedge[base + i + 1];
        int2 e2 = sedge[base + i + 2], e3 = sedge[base + i + 3];

        uint2 kv0 = KV[(unsigned)e0.x * 64u + lane];
        uint2 kv1 = KV[(unsigned)e1.x * 64u + lane];
        uint2 kv2 = KV[(unsigned)e2.x * 64u + lane];
        uint2 kv3 = KV[(unsigned)e3.x * 64u + lane];
        uint2 t0 = QKre[(unsigned)e0.y * 64u + lane];
        uint2 t1 = QKre[(unsigned)e1.y * 64u + lane];
        uint2 t2 = QKre[(unsigned)e2.y * 64u + lane];
        uint2 t3 = QKre[(unsigned)e3.y * 64u + lane];

        float2 kn0 = bf2f2(kv0.x), v0 = bf2f2(kv0.y);
        float2 kn1 = bf2f2(kv1.x), v1 = bf2f2(kv1.y);
        float2 kn2 = bf2f2(kv2.x), v2 = bf2f2(kv2.y);
        float2 kn3 = bf2f2(kv3.x), v3 = bf2f2(kv3.y);
        float2 q0 = bf2f2(t0.x), k0 = bf2f2(t0.y);
        float2 q1 = bf2f2(t1.x), k1 = bf2f2(t1.y);
        float2 q2 = bf2f2(t2.x), k2 = bf2f2(t2.y);
        float2 q3 = bf2f2(t3.x), k3 = bf2f2(t3.y);

        float p0 = (qn.x + q0.x) * (kn0.x + k0.x) + (qn.y + q0.y) * (kn0.y + k0.y);
        float p1 = (qn.x + q1.x) * (kn1.x + k1.x) + (qn.y + q1.y) * (kn1.y + k1.y);
        float p2 = (qn.x + q2.x) * (kn2.x + k2.x) + (qn.y + q2.y) * (kn2.y + k2.y);
        float p3 = (qn.x + q3.x) * (kn3.x + k3.x) + (qn.y + q3.y) * (kn3.y + k3.y);
        #pragma unroll
        for (int m = 32; m >= 1; m >>= 1) {
            p0 += __shfl_xor(p0, m);
            p1 += __shfl_xor(p1, m);
            p2 += __shfl_xor(p2, m);
            p3 += __shfl_xor(p3, m);
        }
        float a0 = p0 * cs, a1 = p1 * cs, a2 = p2 * cs, a3 = p3 * cs;

        // dyn stream (softmax over +a, base 2)
        float mx = fmaxf(fmaxf(a0, a1), fmaxf(a2, a3));
        float mn = fmaxf(m_dyn, mx);
        float f  = exp2f(m_dyn - mn);
        float w0 = exp2f(a0 - mn), w1 = exp2f(a1 - mn);
        float w2 = exp2f(a2 - mn), w3 = exp2f(a3 - mn);
        s_dyn = fmaf(s_dyn, f, (w0 + w1) + (w2 + w3));
        accd.x = fmaf(accd.x, f, fmaf(w0, v0.x, fmaf(w1, v1.x, fmaf(w2, v2.x, w3 * v3.x))));
        accd.y = fmaf(accd.y, f, fmaf(w0, v0.y, fmaf(w1, v1.y, fmaf(w2, v2.y, w3 * v3.y))));
        m_dyn = mn;

        // sta stream (softmax over -a, base 2)
        float nmx = -fminf(fminf(a0, a1), fminf(a2, a3));
        float ms = fmaxf(m_sta, nmx);
        float fs = exp2f(m_sta - ms);
        float u0 = exp2f(-a0 - ms), u1 = exp2f(-a1 - ms);
        float u2 = exp2f(-a2 - ms), u3 = exp2f(-a3 - ms);
        s_sta = fmaf(s_sta, fs, (u0 + u1) + (u2 + u3));
        accs.x = fmaf(accs.x, fs, fmaf(u0, v0.x, fmaf(u1, v1.x, fmaf(u2, v2.x, u3 * v3.x))));
        accs.y = fmaf(accs.y, fs, fmaf(u0, v0.y, fmaf(u1, v1.y, fmaf(u2, v2.y, u3 * v3.y))));
        m_sta = ms;
    }

    for (; i < dcnt; ++i) {
        int2 e = sedge[base + i];
        uint2 kv = KV[(unsigned)e.x * 64u + lane];
        uint2 tt = QKre[(unsigned)e.y * 64u + lane];
        float2 kn = bf2f2(kv.x), v = bf2f2(kv.y);
        float2 q2 = bf2f2(tt.x), k2 = bf2f2(tt.y);
        float pp = (qn.x + q2.x) * (kn.x + k2.x) + (qn.y + q2.y) * (kn.y + k2.y);
        #pragma unroll
        for (int m = 32; m >= 1; m >>= 1) pp += __shfl_xor(pp, m);
        float a = pp * cs;

        float mn = fmaxf(m_dyn, a);
        float fd = exp2f(m_dyn - mn);
        float wd = exp2f(a - mn);
        s_dyn = fmaf(s_dyn, fd, wd);
        accd.x = fmaf(accd.x, fd, wd * v.x);
        accd.y = fmaf(accd.y, fd, wd * v.y);
        m_dyn = mn;

        float ms = fmaxf(m_sta, -a);
        float fs = exp2f(m_sta - ms);
        float ws_ = exp2f(-a - ms);
        s_sta = fmaf(s_sta, fs, ws_);
        accs.x = fmaf(accs.x, fs, ws_ * v.x);
        accs.y = fmaf(accs.y, fs, ws_ * v.y);
        m_sta = ms;
    }

    float denom = (float)(dcnt + 1);
    float id_ = 1.0f / (s_dyn * denom);
    float is_ = 1.0f / (s_sta * denom);
    ((float2*)(out_sta + (long)n * DIMC))[lane] = make_float2(accs.x * is_, accs.y * is_);
    feat_dyn[(unsigned)n * 64u + lane] = pk2(accd.x * id_, accd.y * id_);
}

// ---------------- launch ----------------
extern "C" void kernel_launch(void* const* d_in, const int* in_sizes, int n_in,
                              void* d_out, int out_size, void* d_ws, size_t ws_size,
                              hipStream_t stream)
{
    const float* curr    = (const float*)d_in[0];
    const float* last    = (const float*)d_in[1];
    const float* relemb  = (const float*)d_in[2];
    const float* selfrel = (const float*)d_in[3];
    const float* Wq      = (const float*)d_in[4];
    const float* bq      = (const float*)d_in[5];
    const float* Wk      = (const float*)d_in[6];
    const float* bk      = (const float*)d_in[7];
    const float* Wv      = (const float*)d_in[8];
    const float* bv      = (const float*)d_in[9];
    const float* dynw    = (const float*)d_in[10];
    const int*   eidx    = (const int*)d_in[11];
    const int*   etype   = (const int*)d_in[12];
    float* out = (float*)d_out;

    const int N = in_sizes[0] / DIMC;   // 40000
    const int E = in_sizes[12];         // 400000
    const int R = in_sizes[2] / DIMC;   // 502
    const int* esrc = eidx;
    const int* edst = eidx + E;

    char* wp = (char*)d_ws;
    auto alloc = [&](size_t bytes) { char* r = wp; wp += (bytes + 15) & ~(size_t)15; return r; };
    size_t nd = (size_t)N * DIMC;
    float*          Qn    = (float*)alloc(nd * 4);
    uint2*          KV    = (uint2*)alloc((size_t)N * 64 * 8);       // interleaved K|V bf16 pairs
    unsigned short* Fdb   = (unsigned short*)alloc(nd * 2);
    uint2*          QKre  = (uint2*)alloc((size_t)(R + 1) * 64 * 8); // interleaved Qre|Kre
    unsigned short* FWq   = (unsigned short*)alloc(2048 * 8 * 2);
    unsigned short* FWk   = (unsigned short*)alloc(2048 * 8 * 2);
    unsigned short* FWv   = (unsigned short*)alloc(2048 * 8 * 2);
    unsigned short* FWd   = (unsigned short*)alloc(2048 * 8 * 2);
    int*            deg   = (int*)alloc((size_t)N * 4);
    int*            offs  = (int*)alloc((size_t)N * 4);
    int*            cursor= (int*)alloc((size_t)N * 4);
    int2*           sedge = (int2*)alloc((size_t)E * 8);
    int*            partial = (int*)alloc(256 * 4);

    const int gblk = N / 64;                 // 625
    const int sblk = (N + 1023) / 1024;      // 40

    PrepArgs pa;
    pa.W[0] = Wq;   pa.F[0] = FWq;
    pa.W[1] = Wk;   pa.F[1] = FWk;
    pa.W[2] = Wv;   pa.F[2] = FWv;
    pa.W[3] = dynw; pa.F[3] = FWd;
    hipLaunchKernelGGL(prep_wfrag, dim3(32, 4), dim3(64), 0, stream, pa);

    GemmM3 qkv;
    qkv.Af[0] = curr; qkv.Ab[0] = nullptr; qkv.F[0] = FWq; qkv.bias[0] = nullptr;
    qkv.outf[0] = Qn; qkv.outb[0] = nullptr; qkv.ostride[0] = 1; qkv.ooff[0] = 0;
    qkv.Af[1] = last; qkv.Ab[1] = nullptr; qkv.F[1] = FWk; qkv.bias[1] = nullptr;
    qkv.outf[1] = nullptr; qkv.outb[1] = (unsigned short*)KV; qkv.ostride[1] = 2; qkv.ooff[1] = 0;
    qkv.Af[2] = last; qkv.Ab[2] = nullptr; qkv.F[2] = FWv; qkv.bias[2] = bv;
    qkv.outf[2] = nullptr; qkv.outb[2] = (unsigned short*)KV; qkv.ostride[2] = 2; qkv.ooff[2] = 1;
    hipLaunchKernelGGL(gemm_mfma, dim3(gblk, 3), dim3(256), 0, stream, qkv, N);

    hipLaunchKernelGGL(rel_proj, dim3(R + 1), dim3(128), 0, stream,
                       relemb, selfrel, Wq, bq, Wk, bk, QKre, R);
    hipLaunchKernelGGL(zero_int, dim3((N + 255) / 256), dim3(256), 0, stream, deg, N);
    hipLaunchKernelGGL(hist_kernel, dim3((E + 255) / 256), dim3(256), 0, stream, edst, deg, E);
    hipLaunchKernelGGL(partial_sums, dim3(sblk), dim3(256), 0, stream, deg, partial, N);
    hipLaunchKernelGGL(scan_partials, dim3(1), dim3(256), 0, stream, partial, sblk);
    hipLaunchKernelGGL(write_offsets, dim3(sblk), dim3(256), 0, stream,
                       deg, partial, offs, cursor, N);
    hipLaunchKernelGGL(scatter_kernel, dim3((E + 255) / 256), dim3(256), 0, stream,
                       esrc, edst, etype, cursor, sedge, E);
    hipLaunchKernelGGL(node_kernel, dim3((N + 3) / 4), dim3(256), 0, stream,
                       Qn, KV, QKre, offs, deg, sedge, out, (unsigned*)Fdb, N, R);

    GemmM3 fin;
    fin.Af[0] = nullptr; fin.Ab[0] = Fdb; fin.F[0] = FWd; fin.bias[0] = nullptr;
    fin.outf[0] = out + nd; fin.outb[0] = nullptr; fin.ostride[0] = 1; fin.ooff[0] = 0;
    fin.Af[1] = nullptr; fin.Ab[1] = Fdb; fin.F[1] = FWd; fin.bias[1] = nullptr;
    fin.outf[1] = out + nd; fin.outb[1] = nullptr; fin.ostride[1] = 1; fin.ooff[1] = 0;
    fin.Af[2] = nullptr; fin.Ab[2] = Fdb; fin.F[2] = FWd; fin.bias[2] = nullptr;
    fin.outf[2] = out + nd; fin.outb[2] = nullptr; fin.ostride[2] = 1; fin.ooff[2] = 0;
    hipLaunchKernelGGL(gemm_mfma, dim3(gblk, 1), dim3(256), 0, stream, fin, N);
}